// Round 6
// baseline (190.869 us; speedup 1.0000x reference)
//
#include <hip/hip_runtime.h>
#include <hip/hip_bf16.h>

#define NN 100000
#define NE 1600000
#define NT 6250      // NN/16 node-tiles for MFMA

#define NBUCK  511       // buckets of BRANGE destination nodes
#define BRANGE 196       // fits 8-bit local id
#define CAPB   3584      // bucket capacity: mean 3136, sigma 56 -> 8-sigma margin
#define CHUNK  2048      // edges per bin block
#define NCH    782       // ceil(NE/CHUNK)

typedef __attribute__((ext_vector_type(8))) short bf16x8;
typedef __attribute__((ext_vector_type(4))) float f32x4;

__device__ inline float2 bf16x2_unpack(unsigned v) {
    float2 r;
    r.x = __uint_as_float(v << 16);
    r.y = __uint_as_float(v & 0xffff0000u);
    return r;
}
__device__ inline unsigned bf16x2_pack(float a, float b) {
    __hip_bfloat162 h2(__float2bfloat16(a), __float2bfloat16(b));
    unsigned u;
    __builtin_memcpy(&u, &h2, 4);
    return u;
}

// ---- phase 1: block-local counting sort by bucket + bulk-reserved dense runs.
//      v3: per-wave histograms (intra-wave atomic contention only), single-wave
//      shfl scan (2 barriers, not 16), cols cached in regs across passes. ----
__global__ __launch_bounds__(256) void bin_kernel(const int* __restrict__ rows,
                                                  const int* __restrict__ cols,
                                                  int* __restrict__ cur,   // padded: 1 counter / 64B line
                                                  unsigned* __restrict__ eb) {
    __shared__ int hist4[4][512];
    __shared__ int excl[512];
    __shared__ int lcur[512];
    __shared__ int gbase[512];
    __shared__ unsigned staged[CHUNK];
    __shared__ unsigned short bktarr[CHUNK];
    int t = threadIdx.x;
    int wave = t >> 6;
    int base = blockIdx.x * CHUNK;
    int cnt = min(CHUNK, NE - base);

    #pragma unroll
    for (int u = t; u < 2048; u += 256) ((int*)hist4)[u] = 0;
    __syncthreads();

    int cbuf[CHUNK / 256];
    #pragma unroll
    for (int k = 0; k < CHUNK / 256; k++) {
        int i = k * 256 + t;
        int c = (i < cnt) ? cols[base + i] : -1;
        cbuf[k] = c;
        if (c >= 0) atomicAdd(&hist4[wave][(unsigned)c / BRANGE], 1);
    }
    __syncthreads();

    if (t < 64) {
        // wave-0 scan of 512 entries: 8 chunks of 64 with carry chain
        int carry = 0;
        #pragma unroll
        for (int k = 0; k < 8; k++) {
            int e = k * 64 + t;
            int h = hist4[0][e] + hist4[1][e] + hist4[2][e] + hist4[3][e];
            int inc = h;
            #pragma unroll
            for (int off = 1; off < 64; off <<= 1) {
                int v = __shfl_up(inc, off);
                if (t >= off) inc += v;
            }
            int ex = carry + inc - h;
            excl[e] = ex;
            lcur[e] = ex;
            hist4[0][e] = h;                 // combined count for gbase pass
            carry += __shfl(inc, 63);
        }
    }
    __syncthreads();

    // bulk-reserve global runs (one returning atomic per nonzero bucket)
    #pragma unroll
    for (int u = t; u < 512; u += 256) {
        int h = hist4[0][u];
        gbase[u] = h ? atomicAdd(cur + u * 16, h) : 0;
    }
    __syncthreads();

    // sort records into LDS
    #pragma unroll
    for (int k = 0; k < CHUNK / 256; k++) {
        int i = k * 256 + t;
        int c = cbuf[k];
        if (c >= 0) {
            int r = rows[base + i];
            int bkt = (unsigned)c / BRANGE;
            int lp = atomicAdd(&lcur[bkt], 1);
            staged[lp] = ((unsigned)(c - bkt * BRANGE) << 24) | (unsigned)r;
            bktarr[lp] = (unsigned short)bkt;
        }
    }
    __syncthreads();

    // flat coalesced copy-out: consecutive i in a run -> consecutive gpos
    #pragma unroll
    for (int k = 0; k < CHUNK / 256; k++) {
        int i = k * 256 + t;
        if (i < cnt) {
            int bkt = bktarr[i];
            int pos = gbase[bkt] + (i - excl[bkt]);
            if (pos < CAPB) eb[(size_t)bkt * CAPB + pos] = staged[i];
        }
    }
}

// ---- phase 2: per-bucket node sort + fused xscale. Per-wave hist/rank bases
//      (intra-wave atomics only), records in statically-indexed registers,
//      wave-0 shfl scan, coalesced copy-out, then xs = bf16(x*rsqrt(deg+1))
//      for this bucket's nodes (deg already in LDS). ----
__global__ __launch_bounds__(512) void sortn_kernel(const int* __restrict__ cur,
                                                    const unsigned* __restrict__ eb,
                                                    const float* __restrict__ x,
                                                    int* __restrict__ srcs2,
                                                    int2* __restrict__ nsd,
                                                    unsigned* __restrict__ xs) {
    __shared__ unsigned srcl[CAPB];
    __shared__ int whist[8][256];
    __shared__ int wbase[8][256];
    __shared__ int ndeg[256];
    int b = blockIdx.x, t = threadIdx.x;
    int wave = t >> 6;

    #pragma unroll
    for (int u = t; u < 2048; u += 512) ((int*)whist)[u] = 0;
    __syncthreads();

    int cnt = min(cur[b * 16], CAPB);
    const unsigned* seg = eb + (size_t)b * CAPB;
    unsigned rr[CAPB / 512];                       // 7 regs, statically indexed
    #pragma unroll
    for (int k = 0; k < CAPB / 512; k++) {
        int i = k * 512 + t;
        unsigned r = (i < cnt) ? seg[i] : 0xFFFFFFFFu;
        rr[k] = r;
        if (r != 0xFFFFFFFFu) atomicAdd(&whist[wave][r >> 24], 1);
    }
    __syncthreads();

    if (t < 64) {
        // wave-0 scan of 256 entries (4 chunks of 64, carry chain),
        // also derives per-wave rank bases
        int carry = 0;
        #pragma unroll
        for (int k = 0; k < 4; k++) {
            int e = k * 64 + t;
            int hw[8];
            int h = 0;
            #pragma unroll
            for (int w = 0; w < 8; w++) { hw[w] = whist[w][e]; h += hw[w]; }
            int inc = h;
            #pragma unroll
            for (int off = 1; off < 64; off <<= 1) {
                int v = __shfl_up(inc, off);
                if (t >= off) inc += v;
            }
            int ex = carry + inc - h;
            int acc = ex;
            #pragma unroll
            for (int w = 0; w < 8; w++) { wbase[w][e] = acc; acc += hw[w]; }
            ndeg[e] = h;
            int n = b * BRANGE + e;
            if (e < BRANGE && n < NN) nsd[n] = make_int2(ex, h);
            carry += __shfl(inc, 63);
        }
    }
    __syncthreads();

    // rank: each wave ranks its own records against its own cursor range
    #pragma unroll
    for (int k = 0; k < CAPB / 512; k++) {
        unsigned r = rr[k];
        if (r != 0xFFFFFFFFu) {
            int p = atomicAdd(&wbase[wave][r >> 24], 1);
            srcl[p] = r & 0xFFFFFFu;
        }
    }
    __syncthreads();

    for (int i = t; i < cnt; i += 512)
        srcs2[(size_t)b * CAPB + i] = (int)srcl[i];

    // fused xscale for this bucket's nodes (coalesced x read, deg from LDS)
    int nloc = min(BRANGE, NN - b * BRANGE);
    for (int i = t; i < nloc * 32; i += 512) {
        int nl = i >> 5;
        int d = i & 31;
        int n = b * BRANGE + nl;
        float2 v = *(const float2*)(x + (size_t)n * 64 + d * 2);
        float dv = rsqrtf((float)(ndeg[nl] + 1));
        xs[(size_t)n * 32 + d] = bf16x2_pack(v.x * dv, v.y * dv);
    }
}

// ---- phase 3: gather-aggregate. 4 nodes/wave (16-lane groups, dwordx2 rows),
//      full-grid occupancy, 16 rows in flight per group ----
__global__ __launch_bounds__(256) void gather_kernel(const int* __restrict__ srcs2,
                                                     const int2* __restrict__ nsd,
                                                     const unsigned* __restrict__ xs,
                                                     unsigned* __restrict__ hbu) {
    int lane = threadIdx.x & 63;
    int wave = threadIdx.x >> 6;
    int g  = lane >> 4;            // group (node) within wave: 0..3
    int gl = lane & 15;            // lane within group: covers dims [gl*4, gl*4+4)
    int gb = g << 4;               // group's base lane

    int n = blockIdx.x * 16 + wave * 4 + g;           // grid = NN/16 = 6250 exact
    int2 sd = nsd[n];
    int deg = sd.y;
    int bkt = (unsigned)n / BRANGE;
    const int* seg = srcs2 + (size_t)bkt * CAPB + sd.x;
    const uint2* xsv = (const uint2*)xs;              // 8B per lane per row

    float4 acc = make_float4(0.f, 0.f, 0.f, 0.f);
    for (int base = 0; base < deg; base += 16) {
        // preload up to 16 edge indices for this group's node (one vector load)
        int idx = 0;
        if (base + gl < deg) idx = seg[base + gl];
        int s0 = __shfl(idx, gb);                     // always-valid line (base < deg)
        uint2 v[16];
        #pragma unroll
        for (int j = 0; j < 16; j++) {
            int s = __shfl(idx, gb + j);
            // clamp OOB lanes to a line the group fetches anyway: no serial
            // remainder, no hot pad line, all 16 loads issued back-to-back
            s = (base + j < deg) ? s : s0;
            v[j] = xsv[(size_t)s * 16 + gl];
        }
        #pragma unroll
        for (int j = 0; j < 16; j++) {
            if (base + j < deg) {
                float2 f0 = bf16x2_unpack(v[j].x);
                float2 f1 = bf16x2_unpack(v[j].y);
                acc.x += f0.x; acc.y += f0.y;
                acc.z += f1.x; acc.w += f1.y;
            }
        }
    }
    // self-loop + final D^-1/2 scale; each group stores its full node row (8B/lane)
    uint2 svu = xsv[(size_t)n * 16 + gl];
    float2 sv0 = bf16x2_unpack(svu.x);
    float2 sv1 = bf16x2_unpack(svu.y);
    float dn = rsqrtf((float)(deg + 1));
    uint2 o;
    o.x = bf16x2_pack((acc.x + sv0.x) * dn, (acc.y + sv0.y) * dn);
    o.y = bf16x2_pack((acc.z + sv1.x) * dn, (acc.w + sv1.y) * dn);
    ((uint2*)hbu)[(size_t)n * 16 + gl] = o;
}

// ---- pack Wcat[64 x 192] (3 experts side by side) into B-fragment order, bf16 ----
__global__ void wpack_kernel(const float* __restrict__ W, __hip_bfloat16* __restrict__ Bp) {
    int idx = blockIdx.x * 256 + threadIdx.x;         // 12288 total
    if (idx >= 12288) return;
    int j    = idx & 7;
    int lane = (idx >> 3) & 63;
    int rest = idx >> 9;                              // half*12 + t
    int t    = rest % 12;
    int kh   = rest / 12;
    int k    = kh * 32 + (lane >> 4) * 8 + j;
    int col  = t * 16 + (lane & 15);
    int i    = col >> 6;
    int d    = col & 63;
    Bp[idx] = __float2bfloat16(W[(i * 64 + k) * 64 + d]);
}

// ---- dense: [16-node tile] x [192 outs], K=64 bf16 MFMA; fused bias+relu+gate mix ----
__global__ __launch_bounds__(256) void mfma_kernel(const __hip_bfloat16* __restrict__ hb,
                                                   const short* __restrict__ Bp,
                                                   const float* __restrict__ b,
                                                   const float* __restrict__ gf,
                                                   const float* __restrict__ Wg,
                                                   float* __restrict__ out) {
    int wave = threadIdx.x >> 6;
    int lane = threadIdx.x & 63;
    int tile = blockIdx.x * 4 + wave;
    if (tile >= NT) return;
    int n0 = tile * 16;
    int m = lane & 15, quad = lane >> 4;

    const short* hrow = (const short*)hb + ((size_t)(n0 + m)) * 64 + quad * 8;
    bf16x8 a0 = *(const bf16x8*)(hrow);
    bf16x8 a1 = *(const bf16x8*)(hrow + 32);

    f32x4 acc[12];
    #pragma unroll
    for (int t = 0; t < 12; t++) acc[t] = (f32x4)(0.0f);

    #pragma unroll
    for (int kh = 0; kh < 2; kh++) {
        bf16x8 a = kh ? a1 : a0;
        #pragma unroll
        for (int t = 0; t < 12; t++) {
            bf16x8 bf = *(const bf16x8*)(Bp + ((size_t)((kh * 12 + t) * 64 + lane)) * 8);
            acc[t] = __builtin_amdgcn_mfma_f32_16x16x32_bf16(a, bf, acc[t], 0, 0, 0);
        }
    }

    float wg[12];
    #pragma unroll
    for (int k = 0; k < 12; k++) wg[k] = Wg[k];       // [GATE_C=4][EXPERTS=3] row-major

    #pragma unroll
    for (int reg = 0; reg < 4; reg++) {
        int n = n0 + quad * 4 + reg;
        float4 g = ((const float4*)gf)[n];
        float l0 = (g.x*wg[0] + g.y*wg[3] + g.z*wg[6] + g.w*wg[9])  * (1.0f/101.0f);
        float l1 = (g.x*wg[1] + g.y*wg[4] + g.z*wg[7] + g.w*wg[10]) * (1.0f/101.0f);
        float l2 = (g.x*wg[2] + g.y*wg[5] + g.z*wg[8] + g.w*wg[11]) * (1.0f/101.0f);
        float mx = fmaxf(l0, fmaxf(l1, l2));
        float e0 = __expf(l0 - mx), e1 = __expf(l1 - mx), e2 = __expf(l2 - mx);
        float inv = 1.0f / (e0 + e1 + e2);
        float g0 = e0 * inv, g1 = e1 * inv, g2 = e2 * inv;
        #pragma unroll
        for (int dpos = 0; dpos < 4; dpos++) {
            int d = dpos * 16 + m;
            float v0 = acc[0*4 + dpos][reg] + b[0*64 + d];
            float v1 = acc[1*4 + dpos][reg] + b[1*64 + d];
            float v2 = acc[2*4 + dpos][reg] + b[2*64 + d];
            float o = g0 * fmaxf(v0, 0.f) + g1 * fmaxf(v1, 0.f) + g2 * fmaxf(v2, 0.f);
            out[(size_t)n * 64 + d] = o;
        }
    }
}

extern "C" void kernel_launch(void* const* d_in, const int* in_sizes, int n_in,
                              void* d_out, int out_size, void* d_ws, size_t ws_size,
                              hipStream_t stream) {
    const float* x  = (const float*)d_in[0];
    const int*   ei = (const int*)d_in[1];
    const float* gf = (const float*)d_in[2];
    const float* W  = (const float*)d_in[3];
    const float* b  = (const float*)d_in[4];
    const float* Wg = (const float*)d_in[5];
    float* out = (float*)d_out;
    const int* rows = ei;        // edge_index[0] (sources)
    const int* cols = ei + NE;   // edge_index[1] (targets)

    char* ws = (char*)d_ws;
    size_t off = 0;
    auto alloc = [&](size_t bytes) {
        char* p = ws + off;
        off = (off + bytes + 255) & ~(size_t)255;
        return p;
    };
    int*            cur   = (int*)alloc(512 * 16 * 4);     // 1 counter / 64B line
    unsigned*       eb    = (unsigned*)alloc((size_t)NBUCK * CAPB * 4);
    int*            srcs2 = (int*)alloc((size_t)NBUCK * CAPB * 4);
    int2*           nsd   = (int2*)alloc((size_t)NN * 8);
    unsigned*       xs    = (unsigned*)alloc((size_t)NN * 32 * 4);
    unsigned*       hbu   = (unsigned*)alloc((size_t)NN * 32 * 4);
    __hip_bfloat16* Bp    = (__hip_bfloat16*)alloc(12288 * 2);

    hipMemsetAsync(cur, 0, 512 * 16 * 4, stream);

    bin_kernel<<<NCH, 256, 0, stream>>>(rows, cols, cur, eb);
    sortn_kernel<<<NBUCK, 512, 0, stream>>>(cur, eb, x, srcs2, nsd, xs);
    wpack_kernel<<<48, 256, 0, stream>>>(W, Bp);
    gather_kernel<<<NN / 16, 256, 0, stream>>>(srcs2, nsd, xs, hbu);
    mfma_kernel<<<(NT + 3) / 4, 256, 0, stream>>>((const __hip_bfloat16*)hbu,
                                                  (const short*)Bp, b, gf, Wg, out);
}

// Round 7
// 173.165 us; speedup vs baseline: 1.1022x; 1.1022x over previous
//
#include <hip/hip_runtime.h>
#include <hip/hip_bf16.h>

#define NN 100000
#define NE 1600000
#define NT 6250      // NN/16 node-tiles for MFMA

#define NBUCK  511       // buckets of BRANGE destination nodes
#define BRANGE 196       // fits 8-bit local id
#define CAPB   3584      // bucket capacity: mean 3136, sigma 56 -> 8-sigma margin
#define CHUNK  2048      // edges per bin block
#define NCH    782       // ceil(NE/CHUNK)

typedef __attribute__((ext_vector_type(8))) short bf16x8;
typedef __attribute__((ext_vector_type(4))) float f32x4;

__device__ inline float2 bf16x2_unpack(unsigned v) {
    float2 r;
    r.x = __uint_as_float(v << 16);
    r.y = __uint_as_float(v & 0xffff0000u);
    return r;
}
__device__ inline unsigned bf16x2_pack(float a, float b) {
    __hip_bfloat162 h2(__float2bfloat16(a), __float2bfloat16(b));
    unsigned u;
    __builtin_memcpy(&u, &h2, 4);
    return u;
}

// ---- phase 1: block-local counting sort by bucket + bulk-reserved dense runs.
//      v4: 512 threads/block (8 waves -> ~24 waves/CU latency hiding; bin was
//      occupancy-bound at 26%, not scan- or conflict-bound). Single shared
//      hist (conflicts measured negligible), wave-0 shfl scan, cols in regs. ----
__global__ __launch_bounds__(512) void bin_kernel(const int* __restrict__ rows,
                                                  const int* __restrict__ cols,
                                                  int* __restrict__ cur,   // padded: 1 counter / 64B line
                                                  unsigned* __restrict__ eb) {
    __shared__ int hist[512];
    __shared__ int excl[512];
    __shared__ int lcur[512];
    __shared__ int gbase[512];
    __shared__ unsigned staged[CHUNK];
    __shared__ unsigned short bktarr[CHUNK];
    int t = threadIdx.x;
    int base = blockIdx.x * CHUNK;
    int cnt = min(CHUNK, NE - base);

    if (t < 512) hist[t] = 0;
    __syncthreads();

    int cbuf[CHUNK / 512];
    #pragma unroll
    for (int k = 0; k < CHUNK / 512; k++) {
        int i = k * 512 + t;
        int c = (i < cnt) ? cols[base + i] : -1;
        cbuf[k] = c;
        if (c >= 0) atomicAdd(&hist[(unsigned)c / BRANGE], 1);
    }
    __syncthreads();

    if (t < 64) {
        // wave-0 scan of 512 entries: 8 chunks of 64 with carry chain
        int carry = 0;
        #pragma unroll
        for (int k = 0; k < 8; k++) {
            int e = k * 64 + t;
            int h = hist[e];
            int inc = h;
            #pragma unroll
            for (int off = 1; off < 64; off <<= 1) {
                int v = __shfl_up(inc, off);
                if (t >= off) inc += v;
            }
            int ex = carry + inc - h;
            excl[e] = ex;
            lcur[e] = ex;
            carry += __shfl(inc, 63);
        }
    }
    __syncthreads();

    // bulk-reserve global runs (one returning atomic per nonzero bucket)
    if (t < 512) {
        int h = hist[t];
        gbase[t] = h ? atomicAdd(cur + t * 16, h) : 0;
    }
    __syncthreads();

    // sort records into LDS
    #pragma unroll
    for (int k = 0; k < CHUNK / 512; k++) {
        int i = k * 512 + t;
        int c = cbuf[k];
        if (c >= 0) {
            int r = rows[base + i];
            int bkt = (unsigned)c / BRANGE;
            int lp = atomicAdd(&lcur[bkt], 1);
            staged[lp] = ((unsigned)(c - bkt * BRANGE) << 24) | (unsigned)r;
            bktarr[lp] = (unsigned short)bkt;
        }
    }
    __syncthreads();

    // flat coalesced copy-out: consecutive i in a run -> consecutive gpos
    #pragma unroll
    for (int k = 0; k < CHUNK / 512; k++) {
        int i = k * 512 + t;
        if (i < cnt) {
            int bkt = bktarr[i];
            int pos = gbase[bkt] + (i - excl[bkt]);
            if (pos < CAPB) eb[(size_t)bkt * CAPB + pos] = staged[i];
        }
    }
}

// ---- phase 2: per-bucket node sort (round-5 proven version). Records staged
//      in LDS once, wave-0 shfl scan, rank into LDS srcl, COALESCED copy-out
//      to srcs2. Emits nsd=(start,deg). ----
__global__ __launch_bounds__(512) void sortn_kernel(const int* __restrict__ cur,
                                                    const unsigned* __restrict__ eb,
                                                    int* __restrict__ srcs2,
                                                    int2* __restrict__ nsd) {
    __shared__ unsigned recs[CAPB];
    __shared__ unsigned srcl[CAPB];
    __shared__ int hist[256];
    __shared__ int lcur[256];
    int b = blockIdx.x, t = threadIdx.x;
    if (t < 256) hist[t] = 0;
    __syncthreads();
    int cnt = min(cur[b * 16], CAPB);
    const unsigned* seg = eb + (size_t)b * CAPB;
    for (int i = t; i < cnt; i += 512) {
        unsigned r = seg[i];
        recs[i] = r;
        atomicAdd(&hist[r >> 24], 1);
    }
    __syncthreads();
    if (t < 64) {
        // wave-0 scan of 256 hist entries: 4 per lane + shfl scan of lane sums
        int e = t * 4;
        int h0 = hist[e], h1 = hist[e + 1], h2 = hist[e + 2], h3 = hist[e + 3];
        int lsum = h0 + h1 + h2 + h3;
        int inc = lsum;
        #pragma unroll
        for (int off = 1; off < 64; off <<= 1) {
            int v = __shfl_up(inc, off);
            if (t >= off) inc += v;
        }
        int ex = inc - lsum;                       // exclusive base for entry e
        int e0 = ex, e1 = ex + h0, e2 = e1 + h1, e3 = e2 + h2;
        lcur[e] = e0; lcur[e + 1] = e1; lcur[e + 2] = e2; lcur[e + 3] = e3;
        int n = b * BRANGE + e;
        if (e     < BRANGE && n     < NN) nsd[n]     = make_int2(e0, h0);
        if (e + 1 < BRANGE && n + 1 < NN) nsd[n + 1] = make_int2(e1, h1);
        if (e + 2 < BRANGE && n + 2 < NN) nsd[n + 2] = make_int2(e2, h2);
        if (e + 3 < BRANGE && n + 3 < NN) nsd[n + 3] = make_int2(e3, h3);
    }
    __syncthreads();
    for (int i = t; i < cnt; i += 512) {
        unsigned r = recs[i];
        int p = atomicAdd(&lcur[r >> 24], 1);
        srcl[p] = r & 0xFFFFFFu;
    }
    __syncthreads();
    for (int i = t; i < cnt; i += 512)
        srcs2[(size_t)b * CAPB + i] = (int)srcl[i];
}

// ---- xs = bf16(x * rsqrt(deg+1)) : standalone, high-TLP dense stream ----
__global__ __launch_bounds__(256) void xscale_kernel(const float* __restrict__ x,
                                                     const int2* __restrict__ nsd,
                                                     unsigned* __restrict__ xs) {
    int i = blockIdx.x * 256 + threadIdx.x;           // NN*32 threads exactly
    int n = i >> 5;
    int d = (i & 31) * 2;
    float2 v = *(const float2*)(x + (size_t)n * 64 + d);
    float dv = rsqrtf((float)(nsd[n].y + 1));
    xs[i] = bf16x2_pack(v.x * dv, v.y * dv);
}

// ---- phase 3: gather-aggregate. 4 nodes/wave (16-lane groups, dwordx2 rows),
//      full-grid occupancy, 16 rows in flight per group ----
__global__ __launch_bounds__(256) void gather_kernel(const int* __restrict__ srcs2,
                                                     const int2* __restrict__ nsd,
                                                     const unsigned* __restrict__ xs,
                                                     unsigned* __restrict__ hbu) {
    int lane = threadIdx.x & 63;
    int wave = threadIdx.x >> 6;
    int g  = lane >> 4;            // group (node) within wave: 0..3
    int gl = lane & 15;            // lane within group: covers dims [gl*4, gl*4+4)
    int gb = g << 4;               // group's base lane

    int n = blockIdx.x * 16 + wave * 4 + g;           // grid = NN/16 = 6250 exact
    int2 sd = nsd[n];
    int deg = sd.y;
    int bkt = (unsigned)n / BRANGE;
    const int* seg = srcs2 + (size_t)bkt * CAPB + sd.x;
    const uint2* xsv = (const uint2*)xs;              // 8B per lane per row

    float4 acc = make_float4(0.f, 0.f, 0.f, 0.f);
    for (int base = 0; base < deg; base += 16) {
        // preload up to 16 edge indices for this group's node (one vector load)
        int idx = 0;
        if (base + gl < deg) idx = seg[base + gl];
        int s0 = __shfl(idx, gb);                     // always-valid line (base < deg)
        uint2 v[16];
        #pragma unroll
        for (int j = 0; j < 16; j++) {
            int s = __shfl(idx, gb + j);
            // clamp OOB lanes to a line the group fetches anyway: no serial
            // remainder, no hot pad line, all 16 loads issued back-to-back
            s = (base + j < deg) ? s : s0;
            v[j] = xsv[(size_t)s * 16 + gl];
        }
        #pragma unroll
        for (int j = 0; j < 16; j++) {
            if (base + j < deg) {
                float2 f0 = bf16x2_unpack(v[j].x);
                float2 f1 = bf16x2_unpack(v[j].y);
                acc.x += f0.x; acc.y += f0.y;
                acc.z += f1.x; acc.w += f1.y;
            }
        }
    }
    // self-loop + final D^-1/2 scale; each group stores its full node row (8B/lane)
    uint2 svu = xsv[(size_t)n * 16 + gl];
    float2 sv0 = bf16x2_unpack(svu.x);
    float2 sv1 = bf16x2_unpack(svu.y);
    float dn = rsqrtf((float)(deg + 1));
    uint2 o;
    o.x = bf16x2_pack((acc.x + sv0.x) * dn, (acc.y + sv0.y) * dn);
    o.y = bf16x2_pack((acc.z + sv1.x) * dn, (acc.w + sv1.y) * dn);
    ((uint2*)hbu)[(size_t)n * 16 + gl] = o;
}

// ---- pack Wcat[64 x 192] (3 experts side by side) into B-fragment order, bf16 ----
__global__ void wpack_kernel(const float* __restrict__ W, __hip_bfloat16* __restrict__ Bp) {
    int idx = blockIdx.x * 256 + threadIdx.x;         // 12288 total
    if (idx >= 12288) return;
    int j    = idx & 7;
    int lane = (idx >> 3) & 63;
    int rest = idx >> 9;                              // half*12 + t
    int t    = rest % 12;
    int kh   = rest / 12;
    int k    = kh * 32 + (lane >> 4) * 8 + j;
    int col  = t * 16 + (lane & 15);
    int i    = col >> 6;
    int d    = col & 63;
    Bp[idx] = __float2bfloat16(W[(i * 64 + k) * 64 + d]);
}

// ---- dense: [16-node tile] x [192 outs], K=64 bf16 MFMA; fused bias+relu+gate mix ----
__global__ __launch_bounds__(256) void mfma_kernel(const __hip_bfloat16* __restrict__ hb,
                                                   const short* __restrict__ Bp,
                                                   const float* __restrict__ b,
                                                   const float* __restrict__ gf,
                                                   const float* __restrict__ Wg,
                                                   float* __restrict__ out) {
    int wave = threadIdx.x >> 6;
    int lane = threadIdx.x & 63;
    int tile = blockIdx.x * 4 + wave;
    if (tile >= NT) return;
    int n0 = tile * 16;
    int m = lane & 15, quad = lane >> 4;

    const short* hrow = (const short*)hb + ((size_t)(n0 + m)) * 64 + quad * 8;
    bf16x8 a0 = *(const bf16x8*)(hrow);
    bf16x8 a1 = *(const bf16x8*)(hrow + 32);

    f32x4 acc[12];
    #pragma unroll
    for (int t = 0; t < 12; t++) acc[t] = (f32x4)(0.0f);

    #pragma unroll
    for (int kh = 0; kh < 2; kh++) {
        bf16x8 a = kh ? a1 : a0;
        #pragma unroll
        for (int t = 0; t < 12; t++) {
            bf16x8 bf = *(const bf16x8*)(Bp + ((size_t)((kh * 12 + t) * 64 + lane)) * 8);
            acc[t] = __builtin_amdgcn_mfma_f32_16x16x32_bf16(a, bf, acc[t], 0, 0, 0);
        }
    }

    float wg[12];
    #pragma unroll
    for (int k = 0; k < 12; k++) wg[k] = Wg[k];       // [GATE_C=4][EXPERTS=3] row-major

    #pragma unroll
    for (int reg = 0; reg < 4; reg++) {
        int n = n0 + quad * 4 + reg;
        float4 g = ((const float4*)gf)[n];
        float l0 = (g.x*wg[0] + g.y*wg[3] + g.z*wg[6] + g.w*wg[9])  * (1.0f/101.0f);
        float l1 = (g.x*wg[1] + g.y*wg[4] + g.z*wg[7] + g.w*wg[10]) * (1.0f/101.0f);
        float l2 = (g.x*wg[2] + g.y*wg[5] + g.z*wg[8] + g.w*wg[11]) * (1.0f/101.0f);
        float mx = fmaxf(l0, fmaxf(l1, l2));
        float e0 = __expf(l0 - mx), e1 = __expf(l1 - mx), e2 = __expf(l2 - mx);
        float inv = 1.0f / (e0 + e1 + e2);
        float g0 = e0 * inv, g1 = e1 * inv, g2 = e2 * inv;
        #pragma unroll
        for (int dpos = 0; dpos < 4; dpos++) {
            int d = dpos * 16 + m;
            float v0 = acc[0*4 + dpos][reg] + b[0*64 + d];
            float v1 = acc[1*4 + dpos][reg] + b[1*64 + d];
            float v2 = acc[2*4 + dpos][reg] + b[2*64 + d];
            float o = g0 * fmaxf(v0, 0.f) + g1 * fmaxf(v1, 0.f) + g2 * fmaxf(v2, 0.f);
            out[(size_t)n * 64 + d] = o;
        }
    }
}

extern "C" void kernel_launch(void* const* d_in, const int* in_sizes, int n_in,
                              void* d_out, int out_size, void* d_ws, size_t ws_size,
                              hipStream_t stream) {
    const float* x  = (const float*)d_in[0];
    const int*   ei = (const int*)d_in[1];
    const float* gf = (const float*)d_in[2];
    const float* W  = (const float*)d_in[3];
    const float* b  = (const float*)d_in[4];
    const float* Wg = (const float*)d_in[5];
    float* out = (float*)d_out;
    const int* rows = ei;        // edge_index[0] (sources)
    const int* cols = ei + NE;   // edge_index[1] (targets)

    char* ws = (char*)d_ws;
    size_t off = 0;
    auto alloc = [&](size_t bytes) {
        char* p = ws + off;
        off = (off + bytes + 255) & ~(size_t)255;
        return p;
    };
    int*            cur   = (int*)alloc(512 * 16 * 4);     // 1 counter / 64B line
    unsigned*       eb    = (unsigned*)alloc((size_t)NBUCK * CAPB * 4);
    int*            srcs2 = (int*)alloc((size_t)NBUCK * CAPB * 4);
    int2*           nsd   = (int2*)alloc((size_t)NN * 8);
    unsigned*       xs    = (unsigned*)alloc((size_t)NN * 32 * 4);
    unsigned*       hbu   = (unsigned*)alloc((size_t)NN * 32 * 4);
    __hip_bfloat16* Bp    = (__hip_bfloat16*)alloc(12288 * 2);

    hipMemsetAsync(cur, 0, 512 * 16 * 4, stream);

    bin_kernel<<<NCH, 512, 0, stream>>>(rows, cols, cur, eb);
    sortn_kernel<<<NBUCK, 512, 0, stream>>>(cur, eb, srcs2, nsd);
    xscale_kernel<<<NN * 32 / 256, 256, 0, stream>>>(x, nsd, xs);
    wpack_kernel<<<48, 256, 0, stream>>>(W, Bp);
    gather_kernel<<<NN / 16, 256, 0, stream>>>(srcs2, nsd, xs, hbu);
    mfma_kernel<<<(NT + 3) / 4, 256, 0, stream>>>((const __hip_bfloat16*)hbu,
                                                  (const short*)Bp, b, gf, Wg, out);
}

// Round 8
// 169.283 us; speedup vs baseline: 1.1275x; 1.0229x over previous
//
#include <hip/hip_runtime.h>
#include <hip/hip_bf16.h>

#define NN 100000
#define NE 1600000
#define NT 6250      // NN/16 node-tiles for MFMA

#define NBUCK  511       // buckets of BRANGE destination nodes
#define BRANGE 196       // fits 8-bit local id
#define CAPB   3584      // bucket capacity: mean 3136, sigma 56 -> 8-sigma margin
#define CHUNK  4096      // edges per bin block (runs of ~8 edges = 32B clusters)
#define NCH    391       // ceil(NE/CHUNK)

typedef __attribute__((ext_vector_type(8))) short bf16x8;
typedef __attribute__((ext_vector_type(4))) float f32x4;

__device__ inline float2 bf16x2_unpack(unsigned v) {
    float2 r;
    r.x = __uint_as_float(v << 16);
    r.y = __uint_as_float(v & 0xffff0000u);
    return r;
}
__device__ inline unsigned bf16x2_pack(float a, float b) {
    __hip_bfloat162 h2(__float2bfloat16(a), __float2bfloat16(b));
    unsigned u;
    __builtin_memcpy(&u, &h2, 4);
    return u;
}

// ---- phase 1: block-local counting sort by bucket + bulk-reserved dense runs.
//      v5: CHUNK 4096 @ 512 threads -> runs of ~8 edges (32B) halve store-line
//      fragmentation (bin showed 4x write amp at CHUNK 2048) and halve the
//      per-counter global atomic chain. rows prefetched into regs with cols. ----
__global__ __launch_bounds__(512) void bin_kernel(const int* __restrict__ rows,
                                                  const int* __restrict__ cols,
                                                  int* __restrict__ cur,   // padded: 1 counter / 64B line
                                                  unsigned* __restrict__ eb) {
    __shared__ int hist[512];
    __shared__ int excl[512];
    __shared__ int lcur[512];
    __shared__ int gbase[512];
    __shared__ unsigned staged[CHUNK];
    __shared__ unsigned short bktarr[CHUNK];
    int t = threadIdx.x;
    int base = blockIdx.x * CHUNK;
    int cnt = min(CHUNK, NE - base);

    if (t < 512) hist[t] = 0;
    __syncthreads();

    int cbuf[CHUNK / 512];
    int rbuf[CHUNK / 512];
    #pragma unroll
    for (int k = 0; k < CHUNK / 512; k++) {
        int i = k * 512 + t;
        int c = (i < cnt) ? cols[base + i] : -1;
        int r = (i < cnt) ? rows[base + i] : 0;
        cbuf[k] = c;
        rbuf[k] = r;
        if (c >= 0) atomicAdd(&hist[(unsigned)c / BRANGE], 1);
    }
    __syncthreads();

    if (t < 64) {
        // wave-0 scan of 512 entries: 8 chunks of 64 with carry chain
        int carry = 0;
        #pragma unroll
        for (int k = 0; k < 8; k++) {
            int e = k * 64 + t;
            int h = hist[e];
            int inc = h;
            #pragma unroll
            for (int off = 1; off < 64; off <<= 1) {
                int v = __shfl_up(inc, off);
                if (t >= off) inc += v;
            }
            int ex = carry + inc - h;
            excl[e] = ex;
            lcur[e] = ex;
            carry += __shfl(inc, 63);
        }
    }
    __syncthreads();

    // bulk-reserve global runs (one returning atomic per nonzero bucket)
    if (t < 512) {
        int h = hist[t];
        gbase[t] = h ? atomicAdd(cur + t * 16, h) : 0;
    }
    __syncthreads();

    // sort records into LDS (rows already in regs: pure LDS pass)
    #pragma unroll
    for (int k = 0; k < CHUNK / 512; k++) {
        int c = cbuf[k];
        if (c >= 0) {
            int bkt = (unsigned)c / BRANGE;
            int lp = atomicAdd(&lcur[bkt], 1);
            staged[lp] = ((unsigned)(c - bkt * BRANGE) << 24) | (unsigned)rbuf[k];
            bktarr[lp] = (unsigned short)bkt;
        }
    }
    __syncthreads();

    // flat coalesced copy-out: consecutive i in a run -> consecutive gpos
    #pragma unroll
    for (int k = 0; k < CHUNK / 512; k++) {
        int i = k * 512 + t;
        if (i < cnt) {
            int bkt = bktarr[i];
            int pos = gbase[bkt] + (i - excl[bkt]);
            if (pos < CAPB) eb[(size_t)bkt * CAPB + pos] = staged[i];
        }
    }
}

// ---- phase 2: per-bucket node sort. v2: 1024 threads (was 16 waves/CU
//      grid-starved at 512; now 32 waves/CU). Same algorithm: LDS stage,
//      wave-0 shfl scan, rank, coalesced copy-out. Emits nsd=(start,deg). ----
__global__ __launch_bounds__(1024) void sortn_kernel(const int* __restrict__ cur,
                                                     const unsigned* __restrict__ eb,
                                                     int* __restrict__ srcs2,
                                                     int2* __restrict__ nsd) {
    __shared__ unsigned recs[CAPB];
    __shared__ unsigned srcl[CAPB];
    __shared__ int hist[256];
    __shared__ int lcur[256];
    int b = blockIdx.x, t = threadIdx.x;
    if (t < 256) hist[t] = 0;
    __syncthreads();
    int cnt = min(cur[b * 16], CAPB);
    const unsigned* seg = eb + (size_t)b * CAPB;
    for (int i = t; i < cnt; i += 1024) {
        unsigned r = seg[i];
        recs[i] = r;
        atomicAdd(&hist[r >> 24], 1);
    }
    __syncthreads();
    if (t < 64) {
        // wave-0 scan of 256 hist entries: 4 per lane + shfl scan of lane sums
        int e = t * 4;
        int h0 = hist[e], h1 = hist[e + 1], h2 = hist[e + 2], h3 = hist[e + 3];
        int lsum = h0 + h1 + h2 + h3;
        int inc = lsum;
        #pragma unroll
        for (int off = 1; off < 64; off <<= 1) {
            int v = __shfl_up(inc, off);
            if (t >= off) inc += v;
        }
        int ex = inc - lsum;                       // exclusive base for entry e
        int e0 = ex, e1 = ex + h0, e2 = e1 + h1, e3 = e2 + h2;
        lcur[e] = e0; lcur[e + 1] = e1; lcur[e + 2] = e2; lcur[e + 3] = e3;
        int n = b * BRANGE + e;
        if (e     < BRANGE && n     < NN) nsd[n]     = make_int2(e0, h0);
        if (e + 1 < BRANGE && n + 1 < NN) nsd[n + 1] = make_int2(e1, h1);
        if (e + 2 < BRANGE && n + 2 < NN) nsd[n + 2] = make_int2(e2, h2);
        if (e + 3 < BRANGE && n + 3 < NN) nsd[n + 3] = make_int2(e3, h3);
    }
    __syncthreads();
    for (int i = t; i < cnt; i += 1024) {
        unsigned r = recs[i];
        int p = atomicAdd(&lcur[r >> 24], 1);
        srcl[p] = r & 0xFFFFFFu;
    }
    __syncthreads();
    for (int i = t; i < cnt; i += 1024)
        srcs2[(size_t)b * CAPB + i] = (int)srcl[i];
}

// ---- xs = bf16(x * rsqrt(deg+1)) : standalone, high-TLP dense stream ----
__global__ __launch_bounds__(256) void xscale_kernel(const float* __restrict__ x,
                                                     const int2* __restrict__ nsd,
                                                     unsigned* __restrict__ xs) {
    int i = blockIdx.x * 256 + threadIdx.x;           // NN*32 threads exactly
    int n = i >> 5;
    int d = (i & 31) * 2;
    float2 v = *(const float2*)(x + (size_t)n * 64 + d);
    float dv = rsqrtf((float)(nsd[n].y + 1));
    xs[i] = bf16x2_pack(v.x * dv, v.y * dv);
}

// ---- phase 3: gather-aggregate. 4 nodes/wave (16-lane groups, dwordx2 rows),
//      full-grid occupancy, 16 rows in flight per group ----
__global__ __launch_bounds__(256) void gather_kernel(const int* __restrict__ srcs2,
                                                     const int2* __restrict__ nsd,
                                                     const unsigned* __restrict__ xs,
                                                     unsigned* __restrict__ hbu) {
    int lane = threadIdx.x & 63;
    int wave = threadIdx.x >> 6;
    int g  = lane >> 4;            // group (node) within wave: 0..3
    int gl = lane & 15;            // lane within group: covers dims [gl*4, gl*4+4)
    int gb = g << 4;               // group's base lane

    int n = blockIdx.x * 16 + wave * 4 + g;           // grid = NN/16 = 6250 exact
    int2 sd = nsd[n];
    int deg = sd.y;
    int bkt = (unsigned)n / BRANGE;
    const int* seg = srcs2 + (size_t)bkt * CAPB + sd.x;
    const uint2* xsv = (const uint2*)xs;              // 8B per lane per row

    float4 acc = make_float4(0.f, 0.f, 0.f, 0.f);
    for (int base = 0; base < deg; base += 16) {
        // preload up to 16 edge indices for this group's node (one vector load)
        int idx = 0;
        if (base + gl < deg) idx = seg[base + gl];
        int s0 = __shfl(idx, gb);                     // always-valid line (base < deg)
        uint2 v[16];
        #pragma unroll
        for (int j = 0; j < 16; j++) {
            int s = __shfl(idx, gb + j);
            // clamp OOB lanes to a line the group fetches anyway: no serial
            // remainder, no hot pad line, all 16 loads issued back-to-back
            s = (base + j < deg) ? s : s0;
            v[j] = xsv[(size_t)s * 16 + gl];
        }
        #pragma unroll
        for (int j = 0; j < 16; j++) {
            if (base + j < deg) {
                float2 f0 = bf16x2_unpack(v[j].x);
                float2 f1 = bf16x2_unpack(v[j].y);
                acc.x += f0.x; acc.y += f0.y;
                acc.z += f1.x; acc.w += f1.y;
            }
        }
    }
    // self-loop + final D^-1/2 scale; each group stores its full node row (8B/lane)
    uint2 svu = xsv[(size_t)n * 16 + gl];
    float2 sv0 = bf16x2_unpack(svu.x);
    float2 sv1 = bf16x2_unpack(svu.y);
    float dn = rsqrtf((float)(deg + 1));
    uint2 o;
    o.x = bf16x2_pack((acc.x + sv0.x) * dn, (acc.y + sv0.y) * dn);
    o.y = bf16x2_pack((acc.z + sv1.x) * dn, (acc.w + sv1.y) * dn);
    ((uint2*)hbu)[(size_t)n * 16 + gl] = o;
}

// ---- pack Wcat[64 x 192] (3 experts side by side) into B-fragment order, bf16 ----
__global__ void wpack_kernel(const float* __restrict__ W, __hip_bfloat16* __restrict__ Bp) {
    int idx = blockIdx.x * 256 + threadIdx.x;         // 12288 total
    if (idx >= 12288) return;
    int j    = idx & 7;
    int lane = (idx >> 3) & 63;
    int rest = idx >> 9;                              // half*12 + t
    int t    = rest % 12;
    int kh   = rest / 12;
    int k    = kh * 32 + (lane >> 4) * 8 + j;
    int col  = t * 16 + (lane & 15);
    int i    = col >> 6;
    int d    = col & 63;
    Bp[idx] = __float2bfloat16(W[(i * 64 + k) * 64 + d]);
}

// ---- dense: [16-node tile] x [192 outs], K=64 bf16 MFMA; fused bias+relu+gate mix ----
__global__ __launch_bounds__(256) void mfma_kernel(const __hip_bfloat16* __restrict__ hb,
                                                   const short* __restrict__ Bp,
                                                   const float* __restrict__ b,
                                                   const float* __restrict__ gf,
                                                   const float* __restrict__ Wg,
                                                   float* __restrict__ out) {
    int wave = threadIdx.x >> 6;
    int lane = threadIdx.x & 63;
    int tile = blockIdx.x * 4 + wave;
    if (tile >= NT) return;
    int n0 = tile * 16;
    int m = lane & 15, quad = lane >> 4;

    const short* hrow = (const short*)hb + ((size_t)(n0 + m)) * 64 + quad * 8;
    bf16x8 a0 = *(const bf16x8*)(hrow);
    bf16x8 a1 = *(const bf16x8*)(hrow + 32);

    f32x4 acc[12];
    #pragma unroll
    for (int t = 0; t < 12; t++) acc[t] = (f32x4)(0.0f);

    #pragma unroll
    for (int kh = 0; kh < 2; kh++) {
        bf16x8 a = kh ? a1 : a0;
        #pragma unroll
        for (int t = 0; t < 12; t++) {
            bf16x8 bf = *(const bf16x8*)(Bp + ((size_t)((kh * 12 + t) * 64 + lane)) * 8);
            acc[t] = __builtin_amdgcn_mfma_f32_16x16x32_bf16(a, bf, acc[t], 0, 0, 0);
        }
    }

    float wg[12];
    #pragma unroll
    for (int k = 0; k < 12; k++) wg[k] = Wg[k];       // [GATE_C=4][EXPERTS=3] row-major

    #pragma unroll
    for (int reg = 0; reg < 4; reg++) {
        int n = n0 + quad * 4 + reg;
        float4 g = ((const float4*)gf)[n];
        float l0 = (g.x*wg[0] + g.y*wg[3] + g.z*wg[6] + g.w*wg[9])  * (1.0f/101.0f);
        float l1 = (g.x*wg[1] + g.y*wg[4] + g.z*wg[7] + g.w*wg[10]) * (1.0f/101.0f);
        float l2 = (g.x*wg[2] + g.y*wg[5] + g.z*wg[8] + g.w*wg[11]) * (1.0f/101.0f);
        float mx = fmaxf(l0, fmaxf(l1, l2));
        float e0 = __expf(l0 - mx), e1 = __expf(l1 - mx), e2 = __expf(l2 - mx);
        float inv = 1.0f / (e0 + e1 + e2);
        float g0 = e0 * inv, g1 = e1 * inv, g2 = e2 * inv;
        #pragma unroll
        for (int dpos = 0; dpos < 4; dpos++) {
            int d = dpos * 16 + m;
            float v0 = acc[0*4 + dpos][reg] + b[0*64 + d];
            float v1 = acc[1*4 + dpos][reg] + b[1*64 + d];
            float v2 = acc[2*4 + dpos][reg] + b[2*64 + d];
            float o = g0 * fmaxf(v0, 0.f) + g1 * fmaxf(v1, 0.f) + g2 * fmaxf(v2, 0.f);
            out[(size_t)n * 64 + d] = o;
        }
    }
}

extern "C" void kernel_launch(void* const* d_in, const int* in_sizes, int n_in,
                              void* d_out, int out_size, void* d_ws, size_t ws_size,
                              hipStream_t stream) {
    const float* x  = (const float*)d_in[0];
    const int*   ei = (const int*)d_in[1];
    const float* gf = (const float*)d_in[2];
    const float* W  = (const float*)d_in[3];
    const float* b  = (const float*)d_in[4];
    const float* Wg = (const float*)d_in[5];
    float* out = (float*)d_out;
    const int* rows = ei;        // edge_index[0] (sources)
    const int* cols = ei + NE;   // edge_index[1] (targets)

    char* ws = (char*)d_ws;
    size_t off = 0;
    auto alloc = [&](size_t bytes) {
        char* p = ws + off;
        off = (off + bytes + 255) & ~(size_t)255;
        return p;
    };
    int*            cur   = (int*)alloc(512 * 16 * 4);     // 1 counter / 64B line
    unsigned*       eb    = (unsigned*)alloc((size_t)NBUCK * CAPB * 4);
    int*            srcs2 = (int*)alloc((size_t)NBUCK * CAPB * 4);
    int2*           nsd   = (int2*)alloc((size_t)NN * 8);
    unsigned*       xs    = (unsigned*)alloc((size_t)NN * 32 * 4);
    unsigned*       hbu   = (unsigned*)alloc((size_t)NN * 32 * 4);
    __hip_bfloat16* Bp    = (__hip_bfloat16*)alloc(12288 * 2);

    hipMemsetAsync(cur, 0, 512 * 16 * 4, stream);

    bin_kernel<<<NCH, 512, 0, stream>>>(rows, cols, cur, eb);
    sortn_kernel<<<NBUCK, 1024, 0, stream>>>(cur, eb, srcs2, nsd);
    xscale_kernel<<<NN * 32 / 256, 256, 0, stream>>>(x, nsd, xs);
    wpack_kernel<<<48, 256, 0, stream>>>(W, Bp);
    gather_kernel<<<NN / 16, 256, 0, stream>>>(srcs2, nsd, xs, hbu);
    mfma_kernel<<<(NT + 3) / 4, 256, 0, stream>>>((const __hip_bfloat16*)hbu,
                                                  (const short*)Bp, b, gf, Wg, out);
}

// Round 9
// 165.612 us; speedup vs baseline: 1.1525x; 1.0222x over previous
//
#include <hip/hip_runtime.h>
#include <hip/hip_bf16.h>

#define NN 100000
#define NE 1600000
#define NT 6250      // NN/16 node-tiles

#define NBUCK  511       // buckets of BRANGE destination nodes
#define BRANGE 196       // fits 8-bit local id
#define CAPB   3584      // bucket capacity: mean 3136, sigma 56 -> 8-sigma margin
#define CHUNK  4096      // edges per bin block (runs of ~8 edges = 32B clusters)
#define NCH    391       // ceil(NE/CHUNK)

typedef __attribute__((ext_vector_type(8))) short bf16x8;
typedef __attribute__((ext_vector_type(4))) float f32x4;

__device__ inline float2 bf16x2_unpack(unsigned v) {
    float2 r;
    r.x = __uint_as_float(v << 16);
    r.y = __uint_as_float(v & 0xffff0000u);
    return r;
}
__device__ inline unsigned bf16x2_pack(float a, float b) {
    __hip_bfloat162 h2(__float2bfloat16(a), __float2bfloat16(b));
    unsigned u;
    __builtin_memcpy(&u, &h2, 4);
    return u;
}

// ---- phase 1: block-local counting sort by bucket + bulk-reserved dense runs.
//      CHUNK 4096 @ 512 threads; rows/cols prefetched into regs. ----
__global__ __launch_bounds__(512) void bin_kernel(const int* __restrict__ rows,
                                                  const int* __restrict__ cols,
                                                  int* __restrict__ cur,   // padded: 1 counter / 64B line
                                                  unsigned* __restrict__ eb) {
    __shared__ int hist[512];
    __shared__ int excl[512];
    __shared__ int lcur[512];
    __shared__ int gbase[512];
    __shared__ unsigned staged[CHUNK];
    __shared__ unsigned short bktarr[CHUNK];
    int t = threadIdx.x;
    int base = blockIdx.x * CHUNK;
    int cnt = min(CHUNK, NE - base);

    if (t < 512) hist[t] = 0;
    __syncthreads();

    int cbuf[CHUNK / 512];
    int rbuf[CHUNK / 512];
    #pragma unroll
    for (int k = 0; k < CHUNK / 512; k++) {
        int i = k * 512 + t;
        int c = (i < cnt) ? cols[base + i] : -1;
        int r = (i < cnt) ? rows[base + i] : 0;
        cbuf[k] = c;
        rbuf[k] = r;
        if (c >= 0) atomicAdd(&hist[(unsigned)c / BRANGE], 1);
    }
    __syncthreads();

    if (t < 64) {
        // wave-0 scan of 512 entries: 8 chunks of 64 with carry chain
        int carry = 0;
        #pragma unroll
        for (int k = 0; k < 8; k++) {
            int e = k * 64 + t;
            int h = hist[e];
            int inc = h;
            #pragma unroll
            for (int off = 1; off < 64; off <<= 1) {
                int v = __shfl_up(inc, off);
                if (t >= off) inc += v;
            }
            int ex = carry + inc - h;
            excl[e] = ex;
            lcur[e] = ex;
            carry += __shfl(inc, 63);
        }
    }
    __syncthreads();

    // bulk-reserve global runs (one returning atomic per nonzero bucket)
    if (t < 512) {
        int h = hist[t];
        gbase[t] = h ? atomicAdd(cur + t * 16, h) : 0;
    }
    __syncthreads();

    // sort records into LDS (rows already in regs: pure LDS pass)
    #pragma unroll
    for (int k = 0; k < CHUNK / 512; k++) {
        int c = cbuf[k];
        if (c >= 0) {
            int bkt = (unsigned)c / BRANGE;
            int lp = atomicAdd(&lcur[bkt], 1);
            staged[lp] = ((unsigned)(c - bkt * BRANGE) << 24) | (unsigned)rbuf[k];
            bktarr[lp] = (unsigned short)bkt;
        }
    }
    __syncthreads();

    // flat coalesced copy-out: consecutive i in a run -> consecutive gpos
    #pragma unroll
    for (int k = 0; k < CHUNK / 512; k++) {
        int i = k * 512 + t;
        if (i < cnt) {
            int bkt = bktarr[i];
            int pos = gbase[bkt] + (i - excl[bkt]);
            if (pos < CAPB) eb[(size_t)bkt * CAPB + pos] = staged[i];
        }
    }
}

// ---- phase 2: per-bucket node sort @1024 threads. LDS stage, wave-0 shfl
//      scan, rank, coalesced copy-out. Emits nsd=(start,deg). ----
__global__ __launch_bounds__(1024) void sortn_kernel(const int* __restrict__ cur,
                                                     const unsigned* __restrict__ eb,
                                                     int* __restrict__ srcs2,
                                                     int2* __restrict__ nsd) {
    __shared__ unsigned recs[CAPB];
    __shared__ unsigned srcl[CAPB];
    __shared__ int hist[256];
    __shared__ int lcur[256];
    int b = blockIdx.x, t = threadIdx.x;
    if (t < 256) hist[t] = 0;
    __syncthreads();
    int cnt = min(cur[b * 16], CAPB);
    const unsigned* seg = eb + (size_t)b * CAPB;
    for (int i = t; i < cnt; i += 1024) {
        unsigned r = seg[i];
        recs[i] = r;
        atomicAdd(&hist[r >> 24], 1);
    }
    __syncthreads();
    if (t < 64) {
        // wave-0 scan of 256 hist entries: 4 per lane + shfl scan of lane sums
        int e = t * 4;
        int h0 = hist[e], h1 = hist[e + 1], h2 = hist[e + 2], h3 = hist[e + 3];
        int lsum = h0 + h1 + h2 + h3;
        int inc = lsum;
        #pragma unroll
        for (int off = 1; off < 64; off <<= 1) {
            int v = __shfl_up(inc, off);
            if (t >= off) inc += v;
        }
        int ex = inc - lsum;                       // exclusive base for entry e
        int e0 = ex, e1 = ex + h0, e2 = e1 + h1, e3 = e2 + h2;
        lcur[e] = e0; lcur[e + 1] = e1; lcur[e + 2] = e2; lcur[e + 3] = e3;
        int n = b * BRANGE + e;
        if (e     < BRANGE && n     < NN) nsd[n]     = make_int2(e0, h0);
        if (e + 1 < BRANGE && n + 1 < NN) nsd[n + 1] = make_int2(e1, h1);
        if (e + 2 < BRANGE && n + 2 < NN) nsd[n + 2] = make_int2(e2, h2);
        if (e + 3 < BRANGE && n + 3 < NN) nsd[n + 3] = make_int2(e3, h3);
    }
    __syncthreads();
    for (int i = t; i < cnt; i += 1024) {
        unsigned r = recs[i];
        int p = atomicAdd(&lcur[r >> 24], 1);
        srcl[p] = r & 0xFFFFFFu;
    }
    __syncthreads();
    for (int i = t; i < cnt; i += 1024)
        srcs2[(size_t)b * CAPB + i] = (int)srcl[i];
}

// ---- xs = bf16(x * rsqrt(deg+1)) : standalone, high-TLP dense stream ----
__global__ __launch_bounds__(256) void xscale_kernel(const float* __restrict__ x,
                                                     const int2* __restrict__ nsd,
                                                     unsigned* __restrict__ xs) {
    int i = blockIdx.x * 256 + threadIdx.x;           // NN*32 threads exactly
    int n = i >> 5;
    int d = (i & 31) * 2;
    float2 v = *(const float2*)(x + (size_t)n * 64 + d);
    float dv = rsqrtf((float)(nsd[n].y + 1));
    xs[i] = bf16x2_pack(v.x * dv, v.y * dv);
}

// ---- pack Wcat[64 x 192] (3 experts side by side) into B-fragment order, bf16 ----
__global__ void wpack_kernel(const float* __restrict__ W, __hip_bfloat16* __restrict__ Bp) {
    int idx = blockIdx.x * 256 + threadIdx.x;         // 12288 total
    if (idx >= 12288) return;
    int j    = idx & 7;
    int lane = (idx >> 3) & 63;
    int rest = idx >> 9;                              // half*12 + t
    int t    = rest % 12;
    int kh   = rest / 12;
    int k    = kh * 32 + (lane >> 4) * 8 + j;
    int col  = t * 16 + (lane & 15);
    int i    = col >> 6;
    int d    = col & 63;
    Bp[idx] = __float2bfloat16(W[(i * 64 + k) * 64 + d]);
}

// ---- fused gather + MFMA + epilogue: one block = 16 nodes = one MFMA tile.
//      Phase A (unchanged gather): 4 nodes/wave, 16-lane groups, 16 rows in
//      flight; finished bf16 rows land in a 2KB LDS A-tile (not global).
//      Phase B: wave w = column-group dpos=w; 3 experts x 2 kh = 6 MFMA;
//      fused bias+relu+gate mix; direct f32 store to out. hbu eliminated. ----
__global__ __launch_bounds__(256) void gmm_kernel(const int* __restrict__ srcs2,
                                                  const int2* __restrict__ nsd,
                                                  const unsigned* __restrict__ xs,
                                                  const short* __restrict__ Bp,
                                                  const float* __restrict__ bias,
                                                  const float* __restrict__ gf,
                                                  const float* __restrict__ Wg,
                                                  float* __restrict__ out) {
    __shared__ unsigned atile[16][32];                // 16 nodes x 64 bf16
    int lane = threadIdx.x & 63;
    int wave = threadIdx.x >> 6;
    int g  = lane >> 4;            // group (node) within wave: 0..3
    int gl = lane & 15;            // lane within group: dims [gl*4, gl*4+4)
    int gb = g << 4;               // group's base lane
    int n0 = blockIdx.x * 16;      // grid = NN/16 = 6250 exact

    // ---- phase A: gather (identical memory pattern to proven gather_kernel) ----
    int nl = wave * 4 + g;
    int n = n0 + nl;
    int2 sd = nsd[n];
    int deg = sd.y;
    int bkt = (unsigned)n / BRANGE;
    const int* seg = srcs2 + (size_t)bkt * CAPB + sd.x;
    const uint2* xsv = (const uint2*)xs;              // 8B per lane per row

    float4 acc = make_float4(0.f, 0.f, 0.f, 0.f);
    for (int base = 0; base < deg; base += 16) {
        int idx = 0;
        if (base + gl < deg) idx = seg[base + gl];
        int s0 = __shfl(idx, gb);                     // always-valid line (base < deg)
        uint2 v[16];
        #pragma unroll
        for (int j = 0; j < 16; j++) {
            int s = __shfl(idx, gb + j);
            s = (base + j < deg) ? s : s0;            // clamp OOB to a live line
            v[j] = xsv[(size_t)s * 16 + gl];
        }
        #pragma unroll
        for (int j = 0; j < 16; j++) {
            if (base + j < deg) {
                float2 f0 = bf16x2_unpack(v[j].x);
                float2 f1 = bf16x2_unpack(v[j].y);
                acc.x += f0.x; acc.y += f0.y;
                acc.z += f1.x; acc.w += f1.y;
            }
        }
    }
    uint2 svu = xsv[(size_t)n * 16 + gl];
    float2 sv0 = bf16x2_unpack(svu.x);
    float2 sv1 = bf16x2_unpack(svu.y);
    float dn = rsqrtf((float)(deg + 1));
    uint2 o;
    o.x = bf16x2_pack((acc.x + sv0.x) * dn, (acc.y + sv0.y) * dn);
    o.y = bf16x2_pack((acc.z + sv1.x) * dn, (acc.w + sv1.y) * dn);
    ((uint2*)atile[nl])[gl] = o;                      // LDS, not global
    __syncthreads();

    // ---- phase B: MFMA for this tile; wave w owns column group dpos=w ----
    int m = lane & 15, quad = lane >> 4;
    int dpos = wave;
    const bf16x8* arow = (const bf16x8*)atile[m];     // node n0+m, 8 chunks of 8 bf16
    bf16x8 a0 = arow[quad];                           // k = quad*8 .. +7
    bf16x8 a1 = arow[quad + 4];                       // k+32

    f32x4 ce[3];
    #pragma unroll
    for (int e = 0; e < 3; e++) ce[e] = (f32x4)(0.0f);
    #pragma unroll
    for (int kh = 0; kh < 2; kh++) {
        bf16x8 a = kh ? a1 : a0;
        #pragma unroll
        for (int e = 0; e < 3; e++) {
            bf16x8 bf = *(const bf16x8*)(Bp + ((size_t)((kh * 12 + e * 4 + dpos) * 64 + lane)) * 8);
            ce[e] = __builtin_amdgcn_mfma_f32_16x16x32_bf16(a, bf, ce[e], 0, 0, 0);
        }
    }

    float wg[12];
    #pragma unroll
    for (int k = 0; k < 12; k++) wg[k] = Wg[k];       // [GATE_C=4][EXPERTS=3] row-major

    int d = dpos * 16 + m;
    float b0 = bias[0 * 64 + d], b1 = bias[1 * 64 + d], b2 = bias[2 * 64 + d];
    #pragma unroll
    for (int reg = 0; reg < 4; reg++) {
        int nn = n0 + quad * 4 + reg;
        float4 gv = ((const float4*)gf)[nn];
        float l0 = (gv.x*wg[0] + gv.y*wg[3] + gv.z*wg[6] + gv.w*wg[9])  * (1.0f/101.0f);
        float l1 = (gv.x*wg[1] + gv.y*wg[4] + gv.z*wg[7] + gv.w*wg[10]) * (1.0f/101.0f);
        float l2 = (gv.x*wg[2] + gv.y*wg[5] + gv.z*wg[8] + gv.w*wg[11]) * (1.0f/101.0f);
        float mx = fmaxf(l0, fmaxf(l1, l2));
        float e0 = __expf(l0 - mx), e1 = __expf(l1 - mx), e2 = __expf(l2 - mx);
        float inv = 1.0f / (e0 + e1 + e2);
        float v0 = ce[0][reg] + b0;
        float v1 = ce[1][reg] + b1;
        float v2 = ce[2][reg] + b2;
        float ov = (e0 * fmaxf(v0, 0.f) + e1 * fmaxf(v1, 0.f) + e2 * fmaxf(v2, 0.f)) * inv;
        out[(size_t)nn * 64 + d] = ov;
    }
}

extern "C" void kernel_launch(void* const* d_in, const int* in_sizes, int n_in,
                              void* d_out, int out_size, void* d_ws, size_t ws_size,
                              hipStream_t stream) {
    const float* x  = (const float*)d_in[0];
    const int*   ei = (const int*)d_in[1];
    const float* gf = (const float*)d_in[2];
    const float* W  = (const float*)d_in[3];
    const float* b  = (const float*)d_in[4];
    const float* Wg = (const float*)d_in[5];
    float* out = (float*)d_out;
    const int* rows = ei;        // edge_index[0] (sources)
    const int* cols = ei + NE;   // edge_index[1] (targets)

    char* ws = (char*)d_ws;
    size_t off = 0;
    auto alloc = [&](size_t bytes) {
        char* p = ws + off;
        off = (off + bytes + 255) & ~(size_t)255;
        return p;
    };
    int*            cur   = (int*)alloc(512 * 16 * 4);     // 1 counter / 64B line
    unsigned*       eb    = (unsigned*)alloc((size_t)NBUCK * CAPB * 4);
    int*            srcs2 = (int*)alloc((size_t)NBUCK * CAPB * 4);
    int2*           nsd   = (int2*)alloc((size_t)NN * 8);
    unsigned*       xs    = (unsigned*)alloc((size_t)NN * 32 * 4);
    __hip_bfloat16* Bp    = (__hip_bfloat16*)alloc(12288 * 2);

    hipMemsetAsync(cur, 0, 512 * 16 * 4, stream);

    bin_kernel<<<NCH, 512, 0, stream>>>(rows, cols, cur, eb);
    sortn_kernel<<<NBUCK, 1024, 0, stream>>>(cur, eb, srcs2, nsd);
    xscale_kernel<<<NN * 32 / 256, 256, 0, stream>>>(x, nsd, xs);
    wpack_kernel<<<48, 256, 0, stream>>>(W, Bp);
    gmm_kernel<<<NT, 256, 0, stream>>>(srcs2, nsd, xs, (const short*)Bp, b, gf, Wg, out);
}

// Round 10
// 164.015 us; speedup vs baseline: 1.1637x; 1.0097x over previous
//
#include <hip/hip_runtime.h>
#include <hip/hip_bf16.h>

#define NN 100000
#define NE 1600000
#define NT 6250      // NN/16 node-tiles

#define NBUCK  511       // buckets of BRANGE destination nodes
#define BRANGE 196       // fits 8-bit local id
#define CAPB   3584      // bucket capacity: mean 3136, sigma 56 -> 8-sigma margin
#define CHUNK  4096      // edges per bin block (runs of ~8 edges = 32B clusters)
#define NCH    391       // ceil(NE/CHUNK)

typedef __attribute__((ext_vector_type(8))) short bf16x8;
typedef __attribute__((ext_vector_type(4))) float f32x4;

__device__ inline float2 bf16x2_unpack(unsigned v) {
    float2 r;
    r.x = __uint_as_float(v << 16);
    r.y = __uint_as_float(v & 0xffff0000u);
    return r;
}
__device__ inline unsigned bf16x2_pack(float a, float b) {
    __hip_bfloat162 h2(__float2bfloat16(a), __float2bfloat16(b));
    unsigned u;
    __builtin_memcpy(&u, &h2, 4);
    return u;
}

// ---- phase 1a: per-chunk bucket histogram (no atomics beyond LDS) ----
__global__ __launch_bounds__(512) void binA_kernel(const int* __restrict__ cols,
                                                   int* __restrict__ hist_g) {
    __shared__ int hist[512];
    int t = threadIdx.x;
    int base = blockIdx.x * CHUNK;
    int cnt = min(CHUNK, NE - base);
    hist[t] = 0;
    __syncthreads();
    #pragma unroll
    for (int k = 0; k < CHUNK / 512; k++) {
        int i = k * 512 + t;
        if (i < cnt) atomicAdd(&hist[(unsigned)cols[base + i] / BRANGE], 1);
    }
    __syncthreads();
    hist_g[blockIdx.x * 512 + t] = hist[t];          // coalesced 2KB
}

// ---- phase 1b: per-bucket prefix over chunks -> deterministic run bases.
//      32 lanes per bucket, span-13 segmented shfl scan. Replaces ALL global
//      returning atomics (the suspected 10-25us critical-path stall in bin).
//      Also writes cur[b] = bucket totals (memset eliminated). ----
__global__ __launch_bounds__(512) void scank_kernel(const int* __restrict__ hist_g,
                                                    int* __restrict__ gb,
                                                    int* __restrict__ cur) {
    int t = threadIdx.x;
    int b = blockIdx.x * 16 + (t >> 5);              // 32 blocks x 16 buckets
    int l = t & 31;
    int k0 = l * 13;                                 // 32*13 = 416 >= 391
    int h[13];
    int s = 0;
    #pragma unroll
    for (int i = 0; i < 13; i++) {
        int k = k0 + i;
        h[i] = (k < NCH) ? hist_g[k * 512 + b] : 0;
        s += h[i];
    }
    int inc = s;
    #pragma unroll
    for (int off = 1; off < 32; off <<= 1) {
        int v = __shfl_up(inc, off);                 // stays within 32-lane half
        if (l >= off) inc += v;
    }
    int run = inc - s;                               // exclusive base for lane's span
    #pragma unroll
    for (int i = 0; i < 13; i++) {
        int k = k0 + i;
        if (k < NCH) { gb[k * 512 + b] = run; run += h[i]; }
    }
    if (l == 31) cur[b * 16] = inc;                  // bucket total (padded layout)
}

// ---- phase 1c: counting sort per chunk into deterministic eb runs.
//      Identical to proven bin, with the global atomic reserve replaced by a
//      coalesced gb load. Zero global atomics anywhere. ----
__global__ __launch_bounds__(512) void binB_kernel(const int* __restrict__ rows,
                                                   const int* __restrict__ cols,
                                                   const int* __restrict__ gb,
                                                   unsigned* __restrict__ eb) {
    __shared__ int hist[512];
    __shared__ int excl[512];
    __shared__ int lcur[512];
    __shared__ int gbase[512];
    __shared__ unsigned staged[CHUNK];
    __shared__ unsigned short bktarr[CHUNK];
    int t = threadIdx.x;
    int base = blockIdx.x * CHUNK;
    int cnt = min(CHUNK, NE - base);

    hist[t] = 0;
    gbase[t] = gb[blockIdx.x * 512 + t];             // deterministic run base
    __syncthreads();

    int cbuf[CHUNK / 512];
    int rbuf[CHUNK / 512];
    #pragma unroll
    for (int k = 0; k < CHUNK / 512; k++) {
        int i = k * 512 + t;
        int c = (i < cnt) ? cols[base + i] : -1;
        int r = (i < cnt) ? rows[base + i] : 0;
        cbuf[k] = c;
        rbuf[k] = r;
        if (c >= 0) atomicAdd(&hist[(unsigned)c / BRANGE], 1);
    }
    __syncthreads();

    if (t < 64) {
        // wave-0 scan of 512 entries: 8 chunks of 64 with carry chain
        int carry = 0;
        #pragma unroll
        for (int k = 0; k < 8; k++) {
            int e = k * 64 + t;
            int h = hist[e];
            int inc = h;
            #pragma unroll
            for (int off = 1; off < 64; off <<= 1) {
                int v = __shfl_up(inc, off);
                if (t >= off) inc += v;
            }
            int ex = carry + inc - h;
            excl[e] = ex;
            lcur[e] = ex;
            carry += __shfl(inc, 63);
        }
    }
    __syncthreads();

    // sort records into LDS (rows already in regs: pure LDS pass)
    #pragma unroll
    for (int k = 0; k < CHUNK / 512; k++) {
        int c = cbuf[k];
        if (c >= 0) {
            int bkt = (unsigned)c / BRANGE;
            int lp = atomicAdd(&lcur[bkt], 1);
            staged[lp] = ((unsigned)(c - bkt * BRANGE) << 24) | (unsigned)rbuf[k];
            bktarr[lp] = (unsigned short)bkt;
        }
    }
    __syncthreads();

    // flat coalesced copy-out: consecutive i in a run -> consecutive gpos
    #pragma unroll
    for (int k = 0; k < CHUNK / 512; k++) {
        int i = k * 512 + t;
        if (i < cnt) {
            int bkt = bktarr[i];
            int pos = gbase[bkt] + (i - excl[bkt]);
            if (pos < CAPB) eb[(size_t)bkt * CAPB + pos] = staged[i];
        }
    }
}

// ---- phase 2: per-bucket node sort @1024 threads. LDS stage, wave-0 shfl
//      scan, rank, coalesced copy-out. Emits nsd=(start,deg). ----
__global__ __launch_bounds__(1024) void sortn_kernel(const int* __restrict__ cur,
                                                     const unsigned* __restrict__ eb,
                                                     int* __restrict__ srcs2,
                                                     int2* __restrict__ nsd) {
    __shared__ unsigned recs[CAPB];
    __shared__ unsigned srcl[CAPB];
    __shared__ int hist[256];
    __shared__ int lcur[256];
    int b = blockIdx.x, t = threadIdx.x;
    if (t < 256) hist[t] = 0;
    __syncthreads();
    int cnt = min(cur[b * 16], CAPB);
    const unsigned* seg = eb + (size_t)b * CAPB;
    for (int i = t; i < cnt; i += 1024) {
        unsigned r = seg[i];
        recs[i] = r;
        atomicAdd(&hist[r >> 24], 1);
    }
    __syncthreads();
    if (t < 64) {
        // wave-0 scan of 256 hist entries: 4 per lane + shfl scan of lane sums
        int e = t * 4;
        int h0 = hist[e], h1 = hist[e + 1], h2 = hist[e + 2], h3 = hist[e + 3];
        int lsum = h0 + h1 + h2 + h3;
        int inc = lsum;
        #pragma unroll
        for (int off = 1; off < 64; off <<= 1) {
            int v = __shfl_up(inc, off);
            if (t >= off) inc += v;
        }
        int ex = inc - lsum;                       // exclusive base for entry e
        int e0 = ex, e1 = ex + h0, e2 = e1 + h1, e3 = e2 + h2;
        lcur[e] = e0; lcur[e + 1] = e1; lcur[e + 2] = e2; lcur[e + 3] = e3;
        int n = b * BRANGE + e;
        if (e     < BRANGE && n     < NN) nsd[n]     = make_int2(e0, h0);
        if (e + 1 < BRANGE && n + 1 < NN) nsd[n + 1] = make_int2(e1, h1);
        if (e + 2 < BRANGE && n + 2 < NN) nsd[n + 2] = make_int2(e2, h2);
        if (e + 3 < BRANGE && n + 3 < NN) nsd[n + 3] = make_int2(e3, h3);
    }
    __syncthreads();
    for (int i = t; i < cnt; i += 1024) {
        unsigned r = recs[i];
        int p = atomicAdd(&lcur[r >> 24], 1);
        srcl[p] = r & 0xFFFFFFu;
    }
    __syncthreads();
    for (int i = t; i < cnt; i += 1024)
        srcs2[(size_t)b * CAPB + i] = (int)srcl[i];
}

// ---- xs = bf16(x * rsqrt(deg+1)) : standalone, high-TLP dense stream ----
__global__ __launch_bounds__(256) void xscale_kernel(const float* __restrict__ x,
                                                     const int2* __restrict__ nsd,
                                                     unsigned* __restrict__ xs) {
    int i = blockIdx.x * 256 + threadIdx.x;           // NN*32 threads exactly
    int n = i >> 5;
    int d = (i & 31) * 2;
    float2 v = *(const float2*)(x + (size_t)n * 64 + d);
    float dv = rsqrtf((float)(nsd[n].y + 1));
    xs[i] = bf16x2_pack(v.x * dv, v.y * dv);
}

// ---- pack Wcat[64 x 192] (3 experts side by side) into B-fragment order, bf16 ----
__global__ void wpack_kernel(const float* __restrict__ W, __hip_bfloat16* __restrict__ Bp) {
    int idx = blockIdx.x * 256 + threadIdx.x;         // 12288 total
    if (idx >= 12288) return;
    int j    = idx & 7;
    int lane = (idx >> 3) & 63;
    int rest = idx >> 9;                              // half*12 + t
    int t    = rest % 12;
    int kh   = rest / 12;
    int k    = kh * 32 + (lane >> 4) * 8 + j;
    int col  = t * 16 + (lane & 15);
    int i    = col >> 6;
    int d    = col & 63;
    Bp[idx] = __float2bfloat16(W[(i * 64 + k) * 64 + d]);
}

// ---- fused gather + MFMA + epilogue: one block = 16 nodes = one MFMA tile ----
__global__ __launch_bounds__(256) void gmm_kernel(const int* __restrict__ srcs2,
                                                  const int2* __restrict__ nsd,
                                                  const unsigned* __restrict__ xs,
                                                  const short* __restrict__ Bp,
                                                  const float* __restrict__ bias,
                                                  const float* __restrict__ gf,
                                                  const float* __restrict__ Wg,
                                                  float* __restrict__ out) {
    __shared__ unsigned atile[16][32];                // 16 nodes x 64 bf16
    int lane = threadIdx.x & 63;
    int wave = threadIdx.x >> 6;
    int g  = lane >> 4;            // group (node) within wave: 0..3
    int gl = lane & 15;            // lane within group: dims [gl*4, gl*4+4)
    int gb = g << 4;               // group's base lane
    int n0 = blockIdx.x * 16;      // grid = NN/16 = 6250 exact

    // ---- phase A: gather (proven memory pattern, 16 rows in flight/group) ----
    int nl = wave * 4 + g;
    int n = n0 + nl;
    int2 sd = nsd[n];
    int deg = sd.y;
    int bkt = (unsigned)n / BRANGE;
    const int* seg = srcs2 + (size_t)bkt * CAPB + sd.x;
    const uint2* xsv = (const uint2*)xs;              // 8B per lane per row

    float4 acc = make_float4(0.f, 0.f, 0.f, 0.f);
    for (int base = 0; base < deg; base += 16) {
        int idx = 0;
        if (base + gl < deg) idx = seg[base + gl];
        int s0 = __shfl(idx, gb);                     // always-valid line (base < deg)
        uint2 v[16];
        #pragma unroll
        for (int j = 0; j < 16; j++) {
            int s = __shfl(idx, gb + j);
            s = (base + j < deg) ? s : s0;            // clamp OOB to a live line
            v[j] = xsv[(size_t)s * 16 + gl];
        }
        #pragma unroll
        for (int j = 0; j < 16; j++) {
            if (base + j < deg) {
                float2 f0 = bf16x2_unpack(v[j].x);
                float2 f1 = bf16x2_unpack(v[j].y);
                acc.x += f0.x; acc.y += f0.y;
                acc.z += f1.x; acc.w += f1.y;
            }
        }
    }
    uint2 svu = xsv[(size_t)n * 16 + gl];
    float2 sv0 = bf16x2_unpack(svu.x);
    float2 sv1 = bf16x2_unpack(svu.y);
    float dn = rsqrtf((float)(deg + 1));
    uint2 o;
    o.x = bf16x2_pack((acc.x + sv0.x) * dn, (acc.y + sv0.y) * dn);
    o.y = bf16x2_pack((acc.z + sv1.x) * dn, (acc.w + sv1.y) * dn);
    ((uint2*)atile[nl])[gl] = o;                      // LDS, not global
    __syncthreads();

    // ---- phase B: MFMA for this tile; wave w owns column group dpos=w ----
    int m = lane & 15, quad = lane >> 4;
    int dpos = wave;
    const bf16x8* arow = (const bf16x8*)atile[m];     // node n0+m, 8 chunks of 8 bf16
    bf16x8 a0 = arow[quad];                           // k = quad*8 .. +7
    bf16x8 a1 = arow[quad + 4];                       // k+32

    f32x4 ce[3];
    #pragma unroll
    for (int e = 0; e < 3; e++) ce[e] = (f32x4)(0.0f);
    #pragma unroll
    for (int kh = 0; kh < 2; kh++) {
        bf16x8 a = kh ? a1 : a0;
        #pragma unroll
        for (int e = 0; e < 3; e++) {
            bf16x8 bf = *(const bf16x8*)(Bp + ((size_t)((kh * 12 + e * 4 + dpos) * 64 + lane)) * 8);
            ce[e] = __builtin_amdgcn_mfma_f32_16x16x32_bf16(a, bf, ce[e], 0, 0, 0);
        }
    }

    float wg[12];
    #pragma unroll
    for (int k = 0; k < 12; k++) wg[k] = Wg[k];       // [GATE_C=4][EXPERTS=3] row-major

    int d = dpos * 16 + m;
    float b0 = bias[0 * 64 + d], b1 = bias[1 * 64 + d], b2 = bias[2 * 64 + d];
    #pragma unroll
    for (int reg = 0; reg < 4; reg++) {
        int nn = n0 + quad * 4 + reg;
        float4 gv = ((const float4*)gf)[nn];
        float l0 = (gv.x*wg[0] + gv.y*wg[3] + gv.z*wg[6] + gv.w*wg[9])  * (1.0f/101.0f);
        float l1 = (gv.x*wg[1] + gv.y*wg[4] + gv.z*wg[7] + gv.w*wg[10]) * (1.0f/101.0f);
        float l2 = (gv.x*wg[2] + gv.y*wg[5] + gv.z*wg[8] + gv.w*wg[11]) * (1.0f/101.0f);
        float mx = fmaxf(l0, fmaxf(l1, l2));
        float e0 = __expf(l0 - mx), e1 = __expf(l1 - mx), e2 = __expf(l2 - mx);
        float inv = 1.0f / (e0 + e1 + e2);
        float v0 = ce[0][reg] + b0;
        float v1 = ce[1][reg] + b1;
        float v2 = ce[2][reg] + b2;
        float ov = (e0 * fmaxf(v0, 0.f) + e1 * fmaxf(v1, 0.f) + e2 * fmaxf(v2, 0.f)) * inv;
        out[(size_t)nn * 64 + d] = ov;
    }
}

extern "C" void kernel_launch(void* const* d_in, const int* in_sizes, int n_in,
                              void* d_out, int out_size, void* d_ws, size_t ws_size,
                              hipStream_t stream) {
    const float* x  = (const float*)d_in[0];
    const int*   ei = (const int*)d_in[1];
    const float* gf = (const float*)d_in[2];
    const float* W  = (const float*)d_in[3];
    const float* b  = (const float*)d_in[4];
    const float* Wg = (const float*)d_in[5];
    float* out = (float*)d_out;
    const int* rows = ei;        // edge_index[0] (sources)
    const int* cols = ei + NE;   // edge_index[1] (targets)

    char* ws = (char*)d_ws;
    size_t off = 0;
    auto alloc = [&](size_t bytes) {
        char* p = ws + off;
        off = (off + bytes + 255) & ~(size_t)255;
        return p;
    };
    int*            cur   = (int*)alloc(512 * 16 * 4);     // totals, 1/64B line
    int*            histg = (int*)alloc((size_t)NCH * 512 * 4);
    int*            gbg   = (int*)alloc((size_t)NCH * 512 * 4);
    unsigned*       eb    = (unsigned*)alloc((size_t)NBUCK * CAPB * 4);
    int*            srcs2 = (int*)alloc((size_t)NBUCK * CAPB * 4);
    int2*           nsd   = (int2*)alloc((size_t)NN * 8);
    unsigned*       xs    = (unsigned*)alloc((size_t)NN * 32 * 4);
    __hip_bfloat16* Bp    = (__hip_bfloat16*)alloc(12288 * 2);

    binA_kernel<<<NCH, 512, 0, stream>>>(cols, histg);
    scank_kernel<<<32, 512, 0, stream>>>(histg, gbg, cur);
    binB_kernel<<<NCH, 512, 0, stream>>>(rows, cols, gbg, eb);
    sortn_kernel<<<NBUCK, 1024, 0, stream>>>(cur, eb, srcs2, nsd);
    xscale_kernel<<<NN * 32 / 256, 256, 0, stream>>>(x, nsd, xs);
    wpack_kernel<<<48, 256, 0, stream>>>(W, Bp);
    gmm_kernel<<<NT, 256, 0, stream>>>(srcs2, nsd, xs, (const short*)Bp, b, gf, Wg, out);
}

// Round 11
// 160.801 us; speedup vs baseline: 1.1870x; 1.0200x over previous
//
#include <hip/hip_runtime.h>
#include <hip/hip_bf16.h>

#define NN 100000
#define NE 1600000
#define NT 6250      // NN/16 node-tiles

#define NBUCK  511       // buckets of BRANGE destination nodes
#define BRANGE 196       // fits 8-bit local id
#define CAPB   3584      // bucket capacity: mean 3136, sigma 56 -> 8-sigma margin
#define CHUNK  4096      // edges per bin block (runs of ~8 edges = 32B clusters)
#define NCH    391       // ceil(NE/CHUNK)

typedef __attribute__((ext_vector_type(8))) short bf16x8;
typedef __attribute__((ext_vector_type(4))) float f32x4;

__device__ inline float2 bf16x2_unpack(unsigned v) {
    float2 r;
    r.x = __uint_as_float(v << 16);
    r.y = __uint_as_float(v & 0xffff0000u);
    return r;
}
__device__ inline unsigned bf16x2_pack(float a, float b) {
    __hip_bfloat162 h2(__float2bfloat16(a), __float2bfloat16(b));
    unsigned u;
    __builtin_memcpy(&u, &h2, 4);
    return u;
}

// ---- phase 1a: per-chunk bucket histogram (no atomics beyond LDS) ----
__global__ __launch_bounds__(512) void binA_kernel(const int* __restrict__ cols,
                                                   int* __restrict__ hist_g) {
    __shared__ int hist[512];
    int t = threadIdx.x;
    int base = blockIdx.x * CHUNK;
    int cnt = min(CHUNK, NE - base);
    hist[t] = 0;
    __syncthreads();
    #pragma unroll
    for (int k = 0; k < CHUNK / 512; k++) {
        int i = k * 512 + t;
        if (i < cnt) atomicAdd(&hist[(unsigned)cols[base + i] / BRANGE], 1);
    }
    __syncthreads();
    hist_g[blockIdx.x * 512 + t] = hist[t];          // coalesced 2KB
}

// ---- phase 1b: per-bucket prefix over chunks -> deterministic run bases.
//      Blocks 0..31: scan. Blocks 32..55: wpack (disjoint work, folded launch). ----
__global__ __launch_bounds__(512) void scank_kernel(const int* __restrict__ hist_g,
                                                    int* __restrict__ gb,
                                                    int* __restrict__ cur,
                                                    const float* __restrict__ W,
                                                    __hip_bfloat16* __restrict__ Bp) {
    int t = threadIdx.x;
    if (blockIdx.x >= 32) {
        // ---- wpack: Wcat[64 x 192] -> B-fragment order, bf16 (12288 items) ----
        int idx = (blockIdx.x - 32) * 512 + t;
        if (idx < 12288) {
            int j    = idx & 7;
            int lane = (idx >> 3) & 63;
            int rest = idx >> 9;                      // half*12 + tt
            int tt   = rest % 12;
            int kh   = rest / 12;
            int k    = kh * 32 + (lane >> 4) * 8 + j;
            int col  = tt * 16 + (lane & 15);
            int i    = col >> 6;
            int d    = col & 63;
            Bp[idx] = __float2bfloat16(W[(i * 64 + k) * 64 + d]);
        }
        return;
    }
    int b = blockIdx.x * 16 + (t >> 5);              // 32 blocks x 16 buckets
    int l = t & 31;
    int k0 = l * 13;                                 // 32*13 = 416 >= 391
    int h[13];
    int s = 0;
    #pragma unroll
    for (int i = 0; i < 13; i++) {
        int k = k0 + i;
        h[i] = (k < NCH) ? hist_g[k * 512 + b] : 0;
        s += h[i];
    }
    int inc = s;
    #pragma unroll
    for (int off = 1; off < 32; off <<= 1) {
        int v = __shfl_up(inc, off);                 // stays within 32-lane half
        if (l >= off) inc += v;
    }
    int run = inc - s;                               // exclusive base for lane's span
    #pragma unroll
    for (int i = 0; i < 13; i++) {
        int k = k0 + i;
        if (k < NCH) { gb[k * 512 + b] = run; run += h[i]; }
    }
    if (l == 31) cur[b * 16] = inc;                  // bucket total (padded layout)
}

// ---- phase 1c: counting sort per chunk into deterministic eb runs.
//      v2: hist LOADED from histg (binA already counted) -- deletes the 4096
//      LDS-atomic histogram pass and 2 of 5 barriers; 1024 threads (24 w/CU).
//      Wave-0 scan overlaps the rows/cols register-caching loads. ----
__global__ __launch_bounds__(1024) void binB_kernel(const int* __restrict__ rows,
                                                    const int* __restrict__ cols,
                                                    const int* __restrict__ hist_g,
                                                    const int* __restrict__ gb,
                                                    unsigned* __restrict__ eb) {
    __shared__ int excl[512];
    __shared__ int lcur[512];
    __shared__ int gbase[512];
    __shared__ unsigned staged[CHUNK];
    __shared__ unsigned short bktarr[CHUNK];
    int t = threadIdx.x;
    int base = blockIdx.x * CHUNK;
    int cnt = min(CHUNK, NE - base);

    // record loads into regs (no LDS dependency -> overlaps with scan below)
    int cbuf[CHUNK / 1024];
    int rbuf[CHUNK / 1024];
    #pragma unroll
    for (int k = 0; k < CHUNK / 1024; k++) {
        int i = k * 1024 + t;
        cbuf[k] = (i < cnt) ? cols[base + i] : -1;
        rbuf[k] = (i < cnt) ? rows[base + i] : 0;
    }
    if (t < 512) gbase[t] = gb[blockIdx.x * 512 + t];
    if (t < 64) {
        // preload all 8 hist spans (independent loads), then carry-chain scan
        int h[8];
        #pragma unroll
        for (int k2 = 0; k2 < 8; k2++) h[k2] = hist_g[blockIdx.x * 512 + k2 * 64 + t];
        int carry = 0;
        #pragma unroll
        for (int k2 = 0; k2 < 8; k2++) {
            int inc = h[k2];
            #pragma unroll
            for (int off = 1; off < 64; off <<= 1) {
                int v = __shfl_up(inc, off);
                if (t >= off) inc += v;
            }
            int e = k2 * 64 + t;
            int ex = carry + inc - h[k2];
            excl[e] = ex;
            lcur[e] = ex;
            carry += __shfl(inc, 63);
        }
    }
    __syncthreads();

    // sort records into LDS
    #pragma unroll
    for (int k = 0; k < CHUNK / 1024; k++) {
        int c = cbuf[k];
        if (c >= 0) {
            int bkt = (unsigned)c / BRANGE;
            int lp = atomicAdd(&lcur[bkt], 1);
            staged[lp] = ((unsigned)(c - bkt * BRANGE) << 24) | (unsigned)rbuf[k];
            bktarr[lp] = (unsigned short)bkt;
        }
    }
    __syncthreads();

    // flat coalesced copy-out: consecutive i in a run -> consecutive gpos
    #pragma unroll
    for (int k = 0; k < CHUNK / 1024; k++) {
        int i = k * 1024 + t;
        if (i < cnt) {
            int bkt = bktarr[i];
            int pos = gbase[bkt] + (i - excl[bkt]);
            if (pos < CAPB) eb[(size_t)bkt * CAPB + pos] = staged[i];
        }
    }
}

// ---- phase 2: per-bucket node sort @1024 threads. LDS stage, wave-0 shfl
//      scan, rank, coalesced copy-out. Emits nsd=(start,deg). ----
__global__ __launch_bounds__(1024) void sortn_kernel(const int* __restrict__ cur,
                                                     const unsigned* __restrict__ eb,
                                                     int* __restrict__ srcs2,
                                                     int2* __restrict__ nsd) {
    __shared__ unsigned recs[CAPB];
    __shared__ unsigned srcl[CAPB];
    __shared__ int hist[256];
    __shared__ int lcur[256];
    int b = blockIdx.x, t = threadIdx.x;
    if (t < 256) hist[t] = 0;
    __syncthreads();
    int cnt = min(cur[b * 16], CAPB);
    const unsigned* seg = eb + (size_t)b * CAPB;
    for (int i = t; i < cnt; i += 1024) {
        unsigned r = seg[i];
        recs[i] = r;
        atomicAdd(&hist[r >> 24], 1);
    }
    __syncthreads();
    if (t < 64) {
        // wave-0 scan of 256 hist entries: 4 per lane + shfl scan of lane sums
        int e = t * 4;
        int h0 = hist[e], h1 = hist[e + 1], h2 = hist[e + 2], h3 = hist[e + 3];
        int lsum = h0 + h1 + h2 + h3;
        int inc = lsum;
        #pragma unroll
        for (int off = 1; off < 64; off <<= 1) {
            int v = __shfl_up(inc, off);
            if (t >= off) inc += v;
        }
        int ex = inc - lsum;                       // exclusive base for entry e
        int e0 = ex, e1 = ex + h0, e2 = e1 + h1, e3 = e2 + h2;
        lcur[e] = e0; lcur[e + 1] = e1; lcur[e + 2] = e2; lcur[e + 3] = e3;
        int n = b * BRANGE + e;
        if (e     < BRANGE && n     < NN) nsd[n]     = make_int2(e0, h0);
        if (e + 1 < BRANGE && n + 1 < NN) nsd[n + 1] = make_int2(e1, h1);
        if (e + 2 < BRANGE && n + 2 < NN) nsd[n + 2] = make_int2(e2, h2);
        if (e + 3 < BRANGE && n + 3 < NN) nsd[n + 3] = make_int2(e3, h3);
    }
    __syncthreads();
    for (int i = t; i < cnt; i += 1024) {
        unsigned r = recs[i];
        int p = atomicAdd(&lcur[r >> 24], 1);
        srcl[p] = r & 0xFFFFFFu;
    }
    __syncthreads();
    for (int i = t; i < cnt; i += 1024)
        srcs2[(size_t)b * CAPB + i] = (int)srcl[i];
}

// ---- xs = bf16(x * rsqrt(deg+1)) : standalone, high-TLP dense stream ----
__global__ __launch_bounds__(256) void xscale_kernel(const float* __restrict__ x,
                                                     const int2* __restrict__ nsd,
                                                     unsigned* __restrict__ xs) {
    int i = blockIdx.x * 256 + threadIdx.x;           // NN*32 threads exactly
    int n = i >> 5;
    int d = (i & 31) * 2;
    float2 v = *(const float2*)(x + (size_t)n * 64 + d);
    float dv = rsqrtf((float)(nsd[n].y + 1));
    xs[i] = bf16x2_pack(v.x * dv, v.y * dv);
}

// ---- fused gather + MFMA + epilogue: one block = 16 nodes = one MFMA tile ----
__global__ __launch_bounds__(256) void gmm_kernel(const int* __restrict__ srcs2,
                                                  const int2* __restrict__ nsd,
                                                  const unsigned* __restrict__ xs,
                                                  const short* __restrict__ Bp,
                                                  const float* __restrict__ bias,
                                                  const float* __restrict__ gf,
                                                  const float* __restrict__ Wg,
                                                  float* __restrict__ out) {
    __shared__ unsigned atile[16][32];                // 16 nodes x 64 bf16
    int lane = threadIdx.x & 63;
    int wave = threadIdx.x >> 6;
    int g  = lane >> 4;            // group (node) within wave: 0..3
    int gl = lane & 15;            // lane within group: dims [gl*4, gl*4+4)
    int gb = g << 4;               // group's base lane
    int n0 = blockIdx.x * 16;      // grid = NN/16 = 6250 exact

    // ---- phase A: gather (proven memory pattern, 16 rows in flight/group) ----
    int nl = wave * 4 + g;
    int n = n0 + nl;
    int2 sd = nsd[n];
    int deg = sd.y;
    int bkt = (unsigned)n / BRANGE;
    const int* seg = srcs2 + (size_t)bkt * CAPB + sd.x;
    const uint2* xsv = (const uint2*)xs;              // 8B per lane per row

    float4 acc = make_float4(0.f, 0.f, 0.f, 0.f);
    for (int base = 0; base < deg; base += 16) {
        int idx = 0;
        if (base + gl < deg) idx = seg[base + gl];
        int s0 = __shfl(idx, gb);                     // always-valid line (base < deg)
        uint2 v[16];
        #pragma unroll
        for (int j = 0; j < 16; j++) {
            int s = __shfl(idx, gb + j);
            s = (base + j < deg) ? s : s0;            // clamp OOB to a live line
            v[j] = xsv[(size_t)s * 16 + gl];
        }
        #pragma unroll
        for (int j = 0; j < 16; j++) {
            if (base + j < deg) {
                float2 f0 = bf16x2_unpack(v[j].x);
                float2 f1 = bf16x2_unpack(v[j].y);
                acc.x += f0.x; acc.y += f0.y;
                acc.z += f1.x; acc.w += f1.y;
            }
        }
    }
    uint2 svu = xsv[(size_t)n * 16 + gl];
    float2 sv0 = bf16x2_unpack(svu.x);
    float2 sv1 = bf16x2_unpack(svu.y);
    float dn = rsqrtf((float)(deg + 1));
    uint2 o;
    o.x = bf16x2_pack((acc.x + sv0.x) * dn, (acc.y + sv0.y) * dn);
    o.y = bf16x2_pack((acc.z + sv1.x) * dn, (acc.w + sv1.y) * dn);
    ((uint2*)atile[nl])[gl] = o;                      // LDS, not global
    __syncthreads();

    // ---- phase B: MFMA for this tile; wave w owns column group dpos=w ----
    int m = lane & 15, quad = lane >> 4;
    int dpos = wave;
    const bf16x8* arow = (const bf16x8*)atile[m];     // node n0+m, 8 chunks of 8 bf16
    bf16x8 a0 = arow[quad];                           // k = quad*8 .. +7
    bf16x8 a1 = arow[quad + 4];                       // k+32

    f32x4 ce[3];
    #pragma unroll
    for (int e = 0; e < 3; e++) ce[e] = (f32x4)(0.0f);
    #pragma unroll
    for (int kh = 0; kh < 2; kh++) {
        bf16x8 a = kh ? a1 : a0;
        #pragma unroll
        for (int e = 0; e < 3; e++) {
            bf16x8 bf = *(const bf16x8*)(Bp + ((size_t)((kh * 12 + e * 4 + dpos) * 64 + lane)) * 8);
            ce[e] = __builtin_amdgcn_mfma_f32_16x16x32_bf16(a, bf, ce[e], 0, 0, 0);
        }
    }

    float wg[12];
    #pragma unroll
    for (int k = 0; k < 12; k++) wg[k] = Wg[k];       // [GATE_C=4][EXPERTS=3] row-major

    int d = dpos * 16 + m;
    float b0 = bias[0 * 64 + d], b1 = bias[1 * 64 + d], b2 = bias[2 * 64 + d];
    #pragma unroll
    for (int reg = 0; reg < 4; reg++) {
        int nn = n0 + quad * 4 + reg;
        float4 gv = ((const float4*)gf)[nn];
        float l0 = (gv.x*wg[0] + gv.y*wg[3] + gv.z*wg[6] + gv.w*wg[9])  * (1.0f/101.0f);
        float l1 = (gv.x*wg[1] + gv.y*wg[4] + gv.z*wg[7] + gv.w*wg[10]) * (1.0f/101.0f);
        float l2 = (gv.x*wg[2] + gv.y*wg[5] + gv.z*wg[8] + gv.w*wg[11]) * (1.0f/101.0f);
        float mx = fmaxf(l0, fmaxf(l1, l2));
        float e0 = __expf(l0 - mx), e1 = __expf(l1 - mx), e2 = __expf(l2 - mx);
        float inv = 1.0f / (e0 + e1 + e2);
        float v0 = ce[0][reg] + b0;
        float v1 = ce[1][reg] + b1;
        float v2 = ce[2][reg] + b2;
        float ov = (e0 * fmaxf(v0, 0.f) + e1 * fmaxf(v1, 0.f) + e2 * fmaxf(v2, 0.f)) * inv;
        out[(size_t)nn * 64 + d] = ov;
    }
}

extern "C" void kernel_launch(void* const* d_in, const int* in_sizes, int n_in,
                              void* d_out, int out_size, void* d_ws, size_t ws_size,
                              hipStream_t stream) {
    const float* x  = (const float*)d_in[0];
    const int*   ei = (const int*)d_in[1];
    const float* gf = (const float*)d_in[2];
    const float* W  = (const float*)d_in[3];
    const float* b  = (const float*)d_in[4];
    const float* Wg = (const float*)d_in[5];
    float* out = (float*)d_out;
    const int* rows = ei;        // edge_index[0] (sources)
    const int* cols = ei + NE;   // edge_index[1] (targets)

    char* ws = (char*)d_ws;
    size_t off = 0;
    auto alloc = [&](size_t bytes) {
        char* p = ws + off;
        off = (off + bytes + 255) & ~(size_t)255;
        return p;
    };
    int*            cur   = (int*)alloc(512 * 16 * 4);     // totals, 1/64B line
    int*            histg = (int*)alloc((size_t)NCH * 512 * 4);
    int*            gbg   = (int*)alloc((size_t)NCH * 512 * 4);
    unsigned*       eb    = (unsigned*)alloc((size_t)NBUCK * CAPB * 4);
    int*            srcs2 = (int*)alloc((size_t)NBUCK * CAPB * 4);
    int2*           nsd   = (int2*)alloc((size_t)NN * 8);
    unsigned*       xs    = (unsigned*)alloc((size_t)NN * 32 * 4);
    __hip_bfloat16* Bp    = (__hip_bfloat16*)alloc(12288 * 2);

    binA_kernel<<<NCH, 512, 0, stream>>>(cols, histg);
    scank_kernel<<<56, 512, 0, stream>>>(histg, gbg, cur, W, Bp);
    binB_kernel<<<NCH, 1024, 0, stream>>>(rows, cols, histg, gbg, eb);
    sortn_kernel<<<NBUCK, 1024, 0, stream>>>(cur, eb, srcs2, nsd);
    xscale_kernel<<<NN * 32 / 256, 256, 0, stream>>>(x, nsd, xs);
    gmm_kernel<<<NT, 256, 0, stream>>>(srcs2, nsd, xs, (const short*)Bp, b, gf, Wg, out);
}

// Round 12
// 158.692 us; speedup vs baseline: 1.2028x; 1.0133x over previous
//
#include <hip/hip_runtime.h>
#include <hip/hip_bf16.h>

#define NN 100000
#define NE 1600000
#define NT 6250      // NN/16 node-tiles

#define NBUCK  511       // buckets of BRANGE destination nodes
#define BRANGE 196       // fits 8-bit local id
#define CAPB   3584      // bucket capacity: mean 3136, sigma 56 -> 8-sigma margin
#define CAPP   6720      // padded capacity: CAPB + 196*16 (runs padded to mult of 16)
#define CHUNK  8192      // edges per bin block (runs of ~16 edges = full 64B line)
#define NCH    196       // ceil(NE/CHUNK)

typedef __attribute__((ext_vector_type(8))) short bf16x8;
typedef __attribute__((ext_vector_type(4))) float f32x4;

__device__ inline float2 bf16x2_unpack(unsigned v) {
    float2 r;
    r.x = __uint_as_float(v << 16);
    r.y = __uint_as_float(v & 0xffff0000u);
    return r;
}
__device__ inline unsigned bf16x2_pack(float a, float b) {
    __hip_bfloat162 h2(__float2bfloat16(a), __float2bfloat16(b));
    unsigned u;
    __builtin_memcpy(&u, &h2, 4);
    return u;
}

// ---- phase 1a: per-chunk bucket histogram ----
__global__ __launch_bounds__(1024) void binA_kernel(const int* __restrict__ cols,
                                                    int* __restrict__ hist_g) {
    __shared__ int hist[512];
    int t = threadIdx.x;
    int base = blockIdx.x * CHUNK;
    int cnt = min(CHUNK, NE - base);
    if (t < 512) hist[t] = 0;
    __syncthreads();
    #pragma unroll
    for (int k = 0; k < CHUNK / 1024; k++) {
        int i = k * 1024 + t;
        if (i < cnt) atomicAdd(&hist[(unsigned)cols[base + i] / BRANGE], 1);
    }
    __syncthreads();
    if (t < 512) hist_g[blockIdx.x * 512 + t] = hist[t];
}

// ---- phase 1b: per-bucket prefix over chunks -> deterministic run bases.
//      Blocks 0..31: scan (32 lanes/bucket, span 7: 32*7=224 >= 196 chunks).
//      Blocks 32..55: wpack (disjoint work, folded launch). ----
__global__ __launch_bounds__(512) void scank_kernel(const int* __restrict__ hist_g,
                                                    int* __restrict__ gb,
                                                    int* __restrict__ cur,
                                                    const float* __restrict__ W,
                                                    __hip_bfloat16* __restrict__ Bp) {
    int t = threadIdx.x;
    if (blockIdx.x >= 32) {
        // ---- wpack: Wcat[64 x 192] -> B-fragment order, bf16 (12288 items) ----
        int idx = (blockIdx.x - 32) * 512 + t;
        if (idx < 12288) {
            int j    = idx & 7;
            int lane = (idx >> 3) & 63;
            int rest = idx >> 9;                      // half*12 + tt
            int tt   = rest % 12;
            int kh   = rest / 12;
            int k    = kh * 32 + (lane >> 4) * 8 + j;
            int col  = tt * 16 + (lane & 15);
            int i    = col >> 6;
            int d    = col & 63;
            Bp[idx] = __float2bfloat16(W[(i * 64 + k) * 64 + d]);
        }
        return;
    }
    int b = blockIdx.x * 16 + (t >> 5);              // 32 blocks x 16 buckets
    int l = t & 31;
    int k0 = l * 7;                                  // 32*7 = 224 >= 196
    int h[7];
    int s = 0;
    #pragma unroll
    for (int i = 0; i < 7; i++) {
        int k = k0 + i;
        h[i] = (k < NCH) ? hist_g[k * 512 + b] : 0;
        s += h[i];
    }
    int inc = s;
    #pragma unroll
    for (int off = 1; off < 32; off <<= 1) {
        int v = __shfl_up(inc, off);                 // stays within 32-lane half
        if (l >= off) inc += v;
    }
    int run = inc - s;                               // exclusive base for lane's span
    #pragma unroll
    for (int i = 0; i < 7; i++) {
        int k = k0 + i;
        if (k < NCH) { gb[k * 512 + b] = run; run += h[i]; }
    }
    if (l == 31) cur[b * 16] = inc;                  // bucket total (padded layout)
}

// ---- phase 1c: counting sort per chunk into deterministic eb runs.
//      CHUNK 8192 @ 1024: mean run = 16 edges = one full 64B line -> write
//      amplification ~1x. hist loaded from histg; zero global atomics. ----
__global__ __launch_bounds__(1024) void binB_kernel(const int* __restrict__ rows,
                                                    const int* __restrict__ cols,
                                                    const int* __restrict__ hist_g,
                                                    const int* __restrict__ gb,
                                                    unsigned* __restrict__ eb) {
    __shared__ int excl[512];
    __shared__ int lcur[512];
    __shared__ int gbase[512];
    __shared__ unsigned staged[CHUNK];
    __shared__ unsigned short bktarr[CHUNK];
    int t = threadIdx.x;
    int base = blockIdx.x * CHUNK;
    int cnt = min(CHUNK, NE - base);

    // record loads into regs (no LDS dependency -> overlaps with scan below)
    int cbuf[CHUNK / 1024];
    int rbuf[CHUNK / 1024];
    #pragma unroll
    for (int k = 0; k < CHUNK / 1024; k++) {
        int i = k * 1024 + t;
        cbuf[k] = (i < cnt) ? cols[base + i] : -1;
        rbuf[k] = (i < cnt) ? rows[base + i] : 0;
    }
    if (t < 512) gbase[t] = gb[blockIdx.x * 512 + t];
    if (t < 64) {
        // preload all 8 hist spans (independent loads), then carry-chain scan
        int h[8];
        #pragma unroll
        for (int k2 = 0; k2 < 8; k2++) h[k2] = hist_g[blockIdx.x * 512 + k2 * 64 + t];
        int carry = 0;
        #pragma unroll
        for (int k2 = 0; k2 < 8; k2++) {
            int inc = h[k2];
            #pragma unroll
            for (int off = 1; off < 64; off <<= 1) {
                int v = __shfl_up(inc, off);
                if (t >= off) inc += v;
            }
            int e = k2 * 64 + t;
            int ex = carry + inc - h[k2];
            excl[e] = ex;
            lcur[e] = ex;
            carry += __shfl(inc, 63);
        }
    }
    __syncthreads();

    // sort records into LDS
    #pragma unroll
    for (int k = 0; k < CHUNK / 1024; k++) {
        int c = cbuf[k];
        if (c >= 0) {
            int bkt = (unsigned)c / BRANGE;
            int lp = atomicAdd(&lcur[bkt], 1);
            staged[lp] = ((unsigned)(c - bkt * BRANGE) << 24) | (unsigned)rbuf[k];
            bktarr[lp] = (unsigned short)bkt;
        }
    }
    __syncthreads();

    // flat coalesced copy-out: consecutive i in a run -> consecutive gpos
    #pragma unroll
    for (int k = 0; k < CHUNK / 1024; k++) {
        int i = k * 1024 + t;
        if (i < cnt) {
            int bkt = bktarr[i];
            int pos = gbase[bkt] + (i - excl[bkt]);
            if (pos < CAPB) eb[(size_t)bkt * CAPB + pos] = staged[i];
        }
    }
}

// ---- phase 2: per-bucket node sort with PADDED runs. Each node's run is
//      padded to a multiple of 16 with index NN (zero row in xs) so gather
//      needs zero conditionals. srcl pre-filled with NN; ranks overwrite.
//      Padded total <= 3584 + 196*15 = 6524 < CAPP. ----
__global__ __launch_bounds__(1024) void sortn_kernel(const int* __restrict__ cur,
                                                     const unsigned* __restrict__ eb,
                                                     int* __restrict__ srcs2,
                                                     int2* __restrict__ nsd) {
    __shared__ unsigned recs[CAPB];
    __shared__ unsigned srcl[CAPP];
    __shared__ int hist[256];
    __shared__ int lcur[256];
    __shared__ int ptot_s;
    int b = blockIdx.x, t = threadIdx.x;
    if (t < 256) hist[t] = 0;
    for (int i = t; i < CAPP; i += 1024) srcl[i] = (unsigned)NN;   // pad fill
    __syncthreads();
    int cnt = min(cur[b * 16], CAPB);
    const unsigned* seg = eb + (size_t)b * CAPB;
    for (int i = t; i < cnt; i += 1024) {
        unsigned r = seg[i];
        recs[i] = r;
        atomicAdd(&hist[r >> 24], 1);
    }
    __syncthreads();
    if (t < 64) {
        // wave-0 scan of 256 PADDED counts: 4 per lane + shfl scan of lane sums
        int e = t * 4;
        int h0 = hist[e], h1 = hist[e + 1], h2 = hist[e + 2], h3 = hist[e + 3];
        int p0 = (h0 + 15) & ~15, p1 = (h1 + 15) & ~15;
        int p2 = (h2 + 15) & ~15, p3 = (h3 + 15) & ~15;
        int lsum = p0 + p1 + p2 + p3;
        int inc = lsum;
        #pragma unroll
        for (int off = 1; off < 64; off <<= 1) {
            int v = __shfl_up(inc, off);
            if (t >= off) inc += v;
        }
        int ex = inc - lsum;                       // exclusive padded base
        int e0 = ex, e1 = ex + p0, e2 = e1 + p1, e3 = e2 + p2;
        lcur[e] = e0; lcur[e + 1] = e1; lcur[e + 2] = e2; lcur[e + 3] = e3;
        int n = b * BRANGE + e;
        if (e     < BRANGE && n     < NN) nsd[n]     = make_int2(e0, h0);
        if (e + 1 < BRANGE && n + 1 < NN) nsd[n + 1] = make_int2(e1, h1);
        if (e + 2 < BRANGE && n + 2 < NN) nsd[n + 2] = make_int2(e2, h2);
        if (e + 3 < BRANGE && n + 3 < NN) nsd[n + 3] = make_int2(e3, h3);
        if (t == 63) ptot_s = inc;                 // padded total for copy-out
    }
    __syncthreads();
    for (int i = t; i < cnt; i += 1024) {
        unsigned r = recs[i];
        int p = atomicAdd(&lcur[r >> 24], 1);
        srcl[p] = r & 0xFFFFFFu;
    }
    __syncthreads();
    int ptot = ptot_s;
    for (int i = t; i < ptot; i += 1024)
        srcs2[(size_t)b * CAPP + i] = (int)srcl[i];
}

// ---- xs = bf16(x * rsqrt(deg+1)) + zero row at index NN (gather pad target) ----
__global__ __launch_bounds__(256) void xscale_kernel(const float* __restrict__ x,
                                                     const int2* __restrict__ nsd,
                                                     unsigned* __restrict__ xs) {
    int i = blockIdx.x * 256 + threadIdx.x;
    if (i >= (NN + 1) * 32) return;
    int n = i >> 5;
    if (n == NN) { xs[i] = 0u; return; }              // zero pad row
    int d = (i & 31) * 2;
    float2 v = *(const float2*)(x + (size_t)n * 64 + d);
    float dv = rsqrtf((float)(nsd[n].y + 1));
    xs[i] = bf16x2_pack(v.x * dv, v.y * dv);
}

// ---- fused gather + MFMA + epilogue. Padded runs: gather loop has ZERO
//      conditionals (no clamp, no tail masks) -- pad lanes read the hot zero
//      row and add 0. One block = 16 nodes = one MFMA tile. ----
__global__ __launch_bounds__(256) void gmm_kernel(const int* __restrict__ srcs2,
                                                  const int2* __restrict__ nsd,
                                                  const unsigned* __restrict__ xs,
                                                  const short* __restrict__ Bp,
                                                  const float* __restrict__ bias,
                                                  const float* __restrict__ gf,
                                                  const float* __restrict__ Wg,
                                                  float* __restrict__ out) {
    __shared__ unsigned atile[16][32];                // 16 nodes x 64 bf16
    int lane = threadIdx.x & 63;
    int wave = threadIdx.x >> 6;
    int g  = lane >> 4;            // group (node) within wave: 0..3
    int gl = lane & 15;            // lane within group: dims [gl*4, gl*4+4)
    int gb = g << 4;               // group's base lane
    int n0 = blockIdx.x * 16;      // grid = NN/16 = 6250 exact

    // ---- phase A: gather, unconditional 16-deep windows ----
    int nl = wave * 4 + g;
    int n = n0 + nl;
    int2 sd = nsd[n];
    int deg = sd.y;
    int dgp = (deg + 15) & ~15;                       // padded run length
    int bkt = (unsigned)n / BRANGE;
    const int* seg = srcs2 + (size_t)bkt * CAPP + sd.x;
    const uint2* xsv = (const uint2*)xs;              // 8B per lane per row

    float4 acc = make_float4(0.f, 0.f, 0.f, 0.f);
    for (int base = 0; base < dgp; base += 16) {
        int idx = seg[base + gl];                     // always valid (padded)
        uint2 v[16];
        #pragma unroll
        for (int j = 0; j < 16; j++) {
            int s = __shfl(idx, gb + j);
            v[j] = xsv[(size_t)s * 16 + gl];
        }
        #pragma unroll
        for (int j = 0; j < 16; j++) {
            float2 f0 = bf16x2_unpack(v[j].x);
            float2 f1 = bf16x2_unpack(v[j].y);
            acc.x += f0.x; acc.y += f0.y;
            acc.z += f1.x; acc.w += f1.y;
        }
    }
    uint2 svu = xsv[(size_t)n * 16 + gl];
    float2 sv0 = bf16x2_unpack(svu.x);
    float2 sv1 = bf16x2_unpack(svu.y);
    float dn = rsqrtf((float)(deg + 1));
    uint2 o;
    o.x = bf16x2_pack((acc.x + sv0.x) * dn, (acc.y + sv0.y) * dn);
    o.y = bf16x2_pack((acc.z + sv1.x) * dn, (acc.w + sv1.y) * dn);
    ((uint2*)atile[nl])[gl] = o;                      // LDS, not global
    __syncthreads();

    // ---- phase B: MFMA for this tile; wave w owns column group dpos=w ----
    int m = lane & 15, quad = lane >> 4;
    int dpos = wave;
    const bf16x8* arow = (const bf16x8*)atile[m];     // node n0+m, 8 chunks of 8 bf16
    bf16x8 a0 = arow[quad];                           // k = quad*8 .. +7
    bf16x8 a1 = arow[quad + 4];                       // k+32

    f32x4 ce[3];
    #pragma unroll
    for (int e = 0; e < 3; e++) ce[e] = (f32x4)(0.0f);
    #pragma unroll
    for (int kh = 0; kh < 2; kh++) {
        bf16x8 a = kh ? a1 : a0;
        #pragma unroll
        for (int e = 0; e < 3; e++) {
            bf16x8 bf = *(const bf16x8*)(Bp + ((size_t)((kh * 12 + e * 4 + dpos) * 64 + lane)) * 8);
            ce[e] = __builtin_amdgcn_mfma_f32_16x16x32_bf16(a, bf, ce[e], 0, 0, 0);
        }
    }

    float wg[12];
    #pragma unroll
    for (int k = 0; k < 12; k++) wg[k] = Wg[k];       // [GATE_C=4][EXPERTS=3] row-major

    int d = dpos * 16 + m;
    float b0 = bias[0 * 64 + d], b1 = bias[1 * 64 + d], b2 = bias[2 * 64 + d];
    #pragma unroll
    for (int reg = 0; reg < 4; reg++) {
        int nn = n0 + quad * 4 + reg;
        float4 gv = ((const float4*)gf)[nn];
        float l0 = (gv.x*wg[0] + gv.y*wg[3] + gv.z*wg[6] + gv.w*wg[9])  * (1.0f/101.0f);
        float l1 = (gv.x*wg[1] + gv.y*wg[4] + gv.z*wg[7] + gv.w*wg[10]) * (1.0f/101.0f);
        float l2 = (gv.x*wg[2] + gv.y*wg[5] + gv.z*wg[8] + gv.w*wg[11]) * (1.0f/101.0f);
        float mx = fmaxf(l0, fmaxf(l1, l2));
        float e0 = __expf(l0 - mx), e1 = __expf(l1 - mx), e2 = __expf(l2 - mx);
        float inv = 1.0f / (e0 + e1 + e2);
        float v0 = ce[0][reg] + b0;
        float v1 = ce[1][reg] + b1;
        float v2 = ce[2][reg] + b2;
        float ov = (e0 * fmaxf(v0, 0.f) + e1 * fmaxf(v1, 0.f) + e2 * fmaxf(v2, 0.f)) * inv;
        out[(size_t)nn * 64 + d] = ov;
    }
}

extern "C" void kernel_launch(void* const* d_in, const int* in_sizes, int n_in,
                              void* d_out, int out_size, void* d_ws, size_t ws_size,
                              hipStream_t stream) {
    const float* x  = (const float*)d_in[0];
    const int*   ei = (const int*)d_in[1];
    const float* gf = (const float*)d_in[2];
    const float* W  = (const float*)d_in[3];
    const float* b  = (const float*)d_in[4];
    const float* Wg = (const float*)d_in[5];
    float* out = (float*)d_out;
    const int* rows = ei;        // edge_index[0] (sources)
    const int* cols = ei + NE;   // edge_index[1] (targets)

    char* ws = (char*)d_ws;
    size_t off = 0;
    auto alloc = [&](size_t bytes) {
        char* p = ws + off;
        off = (off + bytes + 255) & ~(size_t)255;
        return p;
    };
    int*            cur   = (int*)alloc(512 * 16 * 4);     // totals, 1/64B line
    int*            histg = (int*)alloc((size_t)NCH * 512 * 4);
    int*            gbg   = (int*)alloc((size_t)NCH * 512 * 4);
    unsigned*       eb    = (unsigned*)alloc((size_t)NBUCK * CAPB * 4);
    int*            srcs2 = (int*)alloc((size_t)NBUCK * CAPP * 4);
    int2*           nsd   = (int2*)alloc((size_t)NN * 8);
    unsigned*       xs    = (unsigned*)alloc((size_t)(NN + 1) * 32 * 4);
    __hip_bfloat16* Bp    = (__hip_bfloat16*)alloc(12288 * 2);

    binA_kernel<<<NCH, 1024, 0, stream>>>(cols, histg);
    scank_kernel<<<56, 512, 0, stream>>>(histg, gbg, cur, W, Bp);
    binB_kernel<<<NCH, 1024, 0, stream>>>(rows, cols, histg, gbg, eb);
    sortn_kernel<<<NBUCK, 1024, 0, stream>>>(cur, eb, srcs2, nsd);
    xscale_kernel<<<((NN + 1) * 32 + 255) / 256, 256, 0, stream>>>(x, nsd, xs);
    gmm_kernel<<<NT, 256, 0, stream>>>(srcs2, nsd, xs, (const short*)Bp, b, gf, Wg, out);
}